// Round 3
// baseline (1125.974 us; speedup 1.0000x reference)
//
#include <hip/hip_runtime.h>
#include <hip/hip_bf16.h>
#include <cstddef>
#include <cstdint>

// ---------------- problem constants ----------------
constexpr int B = 2, L = 2048, DIM = 2048;
constexpr int HK = 16, HV = 32, DK = 128, DV = 128;
constexpr int KEY_DIM = HK * DK;                    // 2048
constexpr int VAL_DIM = HV * DV;                    // 4096
constexpr int CONV_DIM = 2 * KEY_DIM + VAL_DIM;     // 8192
constexpr int NPROJ = CONV_DIM + VAL_DIM + HV + HV; // 12352
constexpr int NPAD  = ((NPROJ + 255) / 256) * 256;  // 12544 (256-tileable)
constexpr size_t ROWS = (size_t)B * L;              // 4096
constexpr float EPS = 1e-6f;
constexpr int CHUNK = 64, NCHUNK = L / CHUNK;       // 32 chunks
constexpr int NCH_TOT = B * HV * NCHUNK;            // 2048 chunk-head blocks

// workspace layout (BYTE offsets). Total ~187 MB (bf16 staging overlaid).
constexpr size_t OFF_QKV  = 0;                                   // bf16
constexpr size_t OFF_Z    = OFF_QKV + ROWS * CONV_DIM * 2;       // bf16 (y in-place)
constexpr size_t OFF_A    = OFF_Z   + ROWS * VAL_DIM * 2;        // f32
constexpr size_t OFF_B    = OFF_A   + ROWS * HV * 4;
constexpr size_t OFF_G    = OFF_B   + ROWS * HV * 4;             // g (log-space)
constexpr size_t OFF_BETA = OFF_G   + ROWS * HV * 4;
constexpr size_t OFF_U    = OFF_BETA + ROWS * HV * 4;            // f32 U = T(BV)
constexpr size_t OFF_WQK  = OFF_U + (size_t)NCH_TOT * CHUNK * DV * 4;  // bf16 Wqk
constexpr size_t WS_NEED_BYTES = OFF_WQK + (size_t)NCH_TOT * CHUNK * CHUNK * 2;
// overlays (lifetime-disjoint):
//   Wcat bf16 (NPAD x DIM, 51.4MB)  @ OFF_U    (dead once gemm_inproj done; U written later)
//   x    bf16 (ROWS x DIM, 16.8MB)  @ OFF_WQK  (dead once gemm_inproj done; Wqk written later)
//   Wout bf16 (DIM x VAL_DIM,16.8MB)@ OFF_U    (written after chunk_scan2, U dead by then)
constexpr size_t OFF_WCAT = OFF_U;
constexpr size_t OFF_XB   = OFF_WQK;
constexpr size_t OFF_WOB  = OFF_U;
static_assert((size_t)NPAD * DIM * 2 <= (size_t)NCH_TOT * CHUNK * DV * 4, "Wcat fits U");

// ---------------- bf16 helpers ----------------
__device__ __forceinline__ float bf2f(unsigned short u) {
    union { float f; uint32_t i; } c; c.i = ((uint32_t)u) << 16; return c.f;
}
__device__ __forceinline__ unsigned short f2bf(float f) {
    union { float f; uint32_t u; } c; c.f = f;
    uint32_t u = c.u + 0x7FFFu + ((c.u >> 16) & 1u);   // RTNE
    return (unsigned short)(u >> 16);
}
__device__ __forceinline__ uint32_t pk2(float a, float b) {
    return (uint32_t)f2bf(a) | ((uint32_t)f2bf(b) << 16);
}

// MFMA fragment types (16x16x32 bf16)
typedef __attribute__((ext_vector_type(8))) short bfrag;   // 8 bf16
typedef __attribute__((ext_vector_type(4))) float ffrag;   // 4 f32

// async global->LDS, 16B per lane (dest is wave-uniform base + lane*16)
__device__ __forceinline__ void gload16(const unsigned short* g, unsigned short* l) {
    __builtin_amdgcn_global_load_lds(
        (const __attribute__((address_space(1))) uint32_t*)g,
        (__attribute__((address_space(3))) uint32_t*)l, 16, 0, 0);
}

// ================= f32 -> bf16 conversion kernels =================
__device__ __forceinline__ const float* w_row_multi(int n, const float* Wq, const float* Wz,
                                                    const float* Wa, const float* Wb) {
    if (n < CONV_DIM)                return Wq + (size_t)n * DIM;
    if (n < CONV_DIM + VAL_DIM)      return Wz + (size_t)(n - CONV_DIM) * DIM;
    if (n < CONV_DIM + VAL_DIM + HV) return Wa + (size_t)(n - CONV_DIM - VAL_DIM) * DIM;
    return Wb + (size_t)(n - CONV_DIM - VAL_DIM - HV) * DIM;
}

__global__ __launch_bounds__(256) void cvt_wcat(
    const float* __restrict__ Wq, const float* __restrict__ Wz,
    const float* __restrict__ Wa, const float* __restrict__ Wb,
    unsigned short* __restrict__ dst)
{
    const int r = blockIdx.x;            // 0..NPAD-1
    const int c = threadIdx.x * 8;       // 256*8 = 2048 = DIM
    uint4 o;
    if (r < NPROJ) {
        const float* s = w_row_multi(r, Wq, Wz, Wa, Wb) + c;
        float4 v0 = *(const float4*)s;
        float4 v1 = *(const float4*)(s + 4);
        o = make_uint4(pk2(v0.x, v0.y), pk2(v0.z, v0.w), pk2(v1.x, v1.y), pk2(v1.z, v1.w));
    } else {
        o = make_uint4(0u, 0u, 0u, 0u);
    }
    *(uint4*)&dst[(size_t)r * DIM + c] = o;
}

__global__ __launch_bounds__(256) void cvt_f32bf(const float* __restrict__ src,
                                                 unsigned short* __restrict__ dst, int cols)
{
    const size_t r = blockIdx.x;
    for (int c = threadIdx.x * 8; c < cols; c += 256 * 8) {
        const float* s = src + r * cols + c;
        float4 v0 = *(const float4*)s;
        float4 v1 = *(const float4*)(s + 4);
        *(uint4*)&dst[r * cols + c] =
            make_uint4(pk2(v0.x, v0.y), pk2(v0.z, v0.w), pk2(v1.x, v1.y), pk2(v1.z, v1.w));
    }
}

// ================= shared GEMM epilogue helper (inproj) =================
__device__ __forceinline__ void store_multi(int m, int n, float v,
                                            unsigned short* qkv, unsigned short* z,
                                            float* a, float* b) {
    if (n < CONV_DIM) {
        qkv[(size_t)m * CONV_DIM + n] = f2bf(v);
    } else if (n < CONV_DIM + VAL_DIM) {
        z[(size_t)m * VAL_DIM + (n - CONV_DIM)] = f2bf(v);
    } else if (n < CONV_DIM + VAL_DIM + HV) {
        a[(size_t)m * HV + (n - CONV_DIM - VAL_DIM)] = v;
    } else if (n < NPROJ) {
        b[(size_t)m * HV + (n - CONV_DIM - VAL_DIM - HV)] = v;
    }
}

constexpr int BK = 64;

// ===================================================================
// 256^2-tile double-buffered inproj GEMM. 512 threads, 8 waves (2Mx4N),
// per-wave output 128x64. LDS: 2 bufs x (A 256x64 + B 256x64) bf16 =128KB.
// Schedule: issue next-tile global_load_lds BEFORE computing current tile;
// single __syncthreads per K-tile (vmcnt drain overlapped with MFMA).
// slot ^= row&7 swizzle (0 bank conflicts, verified) via pre-swizzled src.
// ===================================================================
__global__ __launch_bounds__(512, 2) void gemm_inproj_bf(
    const unsigned short* __restrict__ xb,     // (ROWS, DIM)
    const unsigned short* __restrict__ Wcat,   // (NPAD, DIM), pad rows zero
    unsigned short* __restrict__ qkv, unsigned short* __restrict__ z,
    float* __restrict__ a_out, float* __restrict__ b_out)
{
    extern __shared__ __align__(16) unsigned short lds[];   // 131072 B
    // layout (ushort units): A[buf] at buf*16384, B[buf] at 32768 + buf*16384

    constexpr int NBX = NPAD / 256;            // 49 col panels
    constexpr int NB  = NBX * 16;              // 784 blocks (divisible by 8)
    const int id  = blockIdx.x;
    const int swz = (id & 7) * (NB >> 3) + (id >> 3);
    const int bx  = swz >> 4;                  // 0..48
    const int by  = swz & 15;                  // 0..15
    const int row0 = by * 256;
    const int col0 = bx * 256;

    const int t = threadIdx.x, lane = t & 63, wid = t >> 6;
    const int wr = wid >> 2, wc = wid & 3;
    const int quad = lane >> 4, l16 = lane & 15;

    ffrag acc[8][4];
#pragma unroll
    for (int i = 0; i < 8; ++i)
#pragma unroll
        for (int j = 0; j < 4; ++j) acc[i][j] = (ffrag)0.f;

    // staging: thread covers row srow (of each 64-row group), slot sslot
    const int srow  = t >> 3;                  // 0..63
    const int sslot = t & 7;
    const int scol  = ((sslot ^ (srow & 7)) * 8);   // pre-swizzled source slot
    const unsigned short* aS = xb   + (size_t)(row0 + srow) * DIM + scol;
    const unsigned short* bS = Wcat + (size_t)(col0 + srow) * DIM + scol;
    unsigned short* aD0 = lds + (wid * 8) * 64;            // wave-uniform dest base
    unsigned short* bD0 = lds + 32768 + (wid * 8) * 64;

    const int x7 = l16 & 7;

    auto STAGE = [&](int buf, int k0) {
        unsigned short* aD = aD0 + buf * 16384;
        unsigned short* bD = bD0 + buf * 16384;
#pragma unroll
        for (int j = 0; j < 4; ++j) {
            gload16(aS + (size_t)(j * 64) * DIM + k0, aD + j * 64 * 64);
            gload16(bS + (size_t)(j * 64) * DIM + k0, bD + j * 64 * 64);
        }
    };

    auto COMPUTE = [&](int buf) {
        const unsigned short* A  = lds + buf * 16384;
        const unsigned short* Bm = lds + 32768 + buf * 16384;
#pragma unroll
        for (int kk = 0; kk < 2; ++kk) {
            const int so = ((kk * 4 + quad) ^ x7) * 8;
            bfrag aF[8], bF[4];
#pragma unroll
            for (int m = 0; m < 8; ++m)
                aF[m] = *(const bfrag*)&A[(wr * 128 + m * 16 + l16) * 64 + so];
#pragma unroll
            for (int n = 0; n < 4; ++n)
                bF[n] = *(const bfrag*)&Bm[(wc * 64 + n * 16 + l16) * 64 + so];
#pragma unroll
            for (int m = 0; m < 8; ++m)
#pragma unroll
                for (int n = 0; n < 4; ++n)
                    acc[m][n] = __builtin_amdgcn_mfma_f32_16x16x32_bf16(
                        aF[m], bF[n], acc[m][n], 0, 0, 0);
        }
    };

    STAGE(0, 0);
    __syncthreads();
    for (int kt = 0; kt < DIM / BK; ++kt) {
        if (kt + 1 < DIM / BK) STAGE((kt + 1) & 1, (kt + 1) * BK);
        COMPUTE(kt & 1);
        __syncthreads();   // drains next-tile loads (overlapped with MFMA above)
    }

#pragma unroll
    for (int m = 0; m < 8; ++m)
#pragma unroll
        for (int n = 0; n < 4; ++n) {
            int gr = row0 + wr * 128 + m * 16 + quad * 4;
            int gc = col0 + wc * 64 + n * 16 + l16;
#pragma unroll
            for (int reg = 0; reg < 4; ++reg)
                store_multi(gr + reg, gc, acc[m][n][reg], qkv, z, a_out, b_out);
        }
}

// ===================================================================
// 128^2-tile double-buffered outproj GEMM (same schedule, 256 threads).
// ===================================================================
__global__ __launch_bounds__(256) void gemm_outproj_bf(
    const unsigned short* __restrict__ A,    // (ROWS, VAL_DIM)
    const unsigned short* __restrict__ Wb,   // (DIM, VAL_DIM)
    float* __restrict__ C)                   // (ROWS, DIM)
{
    __shared__ __align__(16) unsigned short As[2][128 * BK];
    __shared__ __align__(16) unsigned short Bs[2][128 * BK];

    constexpr int NB = (ROWS / 128) * (DIM / 128);   // 512
    const int id  = blockIdx.x;
    const int swz = (id & 7) * (NB >> 3) + (id >> 3);
    const int bx  = swz >> 5;                  // 0..15 col block
    const int by  = swz & 31;                  // 0..31 row block
    const int row0 = by * 128;
    const int col0 = bx * 128;

    const int t = threadIdx.x, lane = t & 63, wid = t >> 6;
    const int quad = lane >> 4, l16 = lane & 15;
    const int wm = (wid >> 1) * 64, wn = (wid & 1) * 64;

    ffrag acc[4][4];
#pragma unroll
    for (int i = 0; i < 4; ++i)
#pragma unroll
        for (int j = 0; j < 4; ++j) acc[i][j] = (ffrag)0.f;

    const int srow  = t >> 3;                  // 0..31
    const int sslot = t & 7;
    const int scol  = ((sslot ^ (srow & 7)) * 8);
    const unsigned short* aS = A  + (size_t)(row0 + srow) * VAL_DIM + scol;
    const unsigned short* bS = Wb + (size_t)(col0 + srow) * VAL_DIM + scol;

    const int aBase = (wm + l16) * BK;
    const int bBase = (wn + l16) * BK;
    const int x7 = l16 & 7;

    auto STAGE = [&](int buf, int k0) {
        unsigned short* aD = &As[buf][(wid * 8) * 64];
        unsigned short* bD = &Bs[buf][(wid * 8) * 64];
#pragma unroll
        for (int j = 0; j < 4; ++j) {
            gload16(aS + (size_t)(j * 32) * VAL_DIM + k0, aD + j * 32 * 64);
            gload16(bS + (size_t)(j * 32) * VAL_DIM + k0, bD + j * 32 * 64);
        }
    };

    auto COMPUTE = [&](int buf) {
#pragma unroll
        for (int kk = 0; kk < 2; ++kk) {
            const int so = ((kk * 4 + quad) ^ x7) * 8;
            bfrag aF[4], bF[4];
#pragma unroll
            for (int mt = 0; mt < 4; ++mt) aF[mt] = *(const bfrag*)&As[buf][aBase + mt * 16 * BK + so];
#pragma unroll
            for (int nt = 0; nt < 4; ++nt) bF[nt] = *(const bfrag*)&Bs[buf][bBase + nt * 16 * BK + so];
#pragma unroll
            for (int mt = 0; mt < 4; ++mt)
#pragma unroll
                for (int nt = 0; nt < 4; ++nt)
                    acc[mt][nt] = __builtin_amdgcn_mfma_f32_16x16x32_bf16(
                        aF[mt], bF[nt], acc[mt][nt], 0, 0, 0);
        }
    };

    STAGE(0, 0);
    __syncthreads();
    for (int kt = 0; kt < VAL_DIM / BK; ++kt) {
        if (kt + 1 < VAL_DIM / BK) STAGE((kt + 1) & 1, (kt + 1) * BK);
        COMPUTE(kt & 1);
        __syncthreads();
    }

#pragma unroll
    for (int mt = 0; mt < 4; ++mt)
#pragma unroll
        for (int nt = 0; nt < 4; ++nt) {
            int gr = row0 + wm + mt * 16 + quad * 4;
            int gc = col0 + wn + nt * 16 + l16;
#pragma unroll
            for (int reg = 0; reg < 4; ++reg)
                C[(size_t)(gr + reg) * DIM + gc] = acc[mt][nt][reg];
        }
}

// ================= depthwise causal conv1d + SiLU =================
__global__ __launch_bounds__(256) void conv_silu(unsigned short* __restrict__ qkv,
                                                 const float* __restrict__ conv_w)
{
    int idx = blockIdx.x * blockDim.x + threadIdx.x;
    int b = idx >> 13;
    int c = idx & (CONV_DIM - 1);
    const float w0 = conv_w[c * 4 + 0];
    const float w1 = conv_w[c * 4 + 1];
    const float w2 = conv_w[c * 4 + 2];
    const float w3 = conv_w[c * 4 + 3];
    unsigned short* p = qkv + (size_t)b * L * CONV_DIM + c;
    float x0 = 0.f, x1 = 0.f, x2 = 0.f;
    for (int l0 = 0; l0 < L; l0 += 8) {
        float xv[8];
#pragma unroll
        for (int j = 0; j < 8; ++j) xv[j] = bf2f(p[(size_t)(l0 + j) * CONV_DIM]);
#pragma unroll
        for (int j = 0; j < 8; ++j) {
            float h = w0 * x0 + w1 * x1 + w2 * x2 + w3 * xv[j];
            float s = h / (1.f + __expf(-h));
            p[(size_t)(l0 + j) * CONV_DIM] = f2bf(s);
            x0 = x1; x1 = x2; x2 = xv[j];
        }
    }
}

// ================= l2norm of q,k heads =================
__global__ __launch_bounds__(256) void normqk(unsigned short* __restrict__ qkv)
{
    int wid  = blockIdx.x * 4 + (threadIdx.x >> 6);
    int lane = threadIdx.x & 63;
    int hk  = wid & 15;
    int sel = (wid >> 4) & 1;
    int row = wid >> 5;
    unsigned short* p = qkv + (size_t)row * CONV_DIM + sel * KEY_DIM + hk * DK;
    float x0 = bf2f(p[lane]), x1 = bf2f(p[lane + 64]);
    float ss = x0 * x0 + x1 * x1;
#pragma unroll
    for (int o = 32; o >= 1; o >>= 1) ss += __shfl_xor(ss, o);
    float sc = rsqrtf(ss + 1e-6f);
    if (sel == 0) sc *= 0.08838834764831845f;   // DK^-0.5
    p[lane]      = f2bf(x0 * sc);
    p[lane + 64] = f2bf(x1 * sc);
}

// ================= gate coefficients: g (log) and beta =================
__global__ __launch_bounds__(256) void gatecoef(const float* __restrict__ a_buf,
                                                const float* __restrict__ b_buf,
                                                const float* __restrict__ A_log,
                                                const float* __restrict__ dt_bias,
                                                float* __restrict__ glog,
                                                float* __restrict__ beta)
{
    int idx = blockIdx.x * blockDim.x + threadIdx.x;
    int h = idx & (HV - 1);
    float av = a_buf[idx];
    float bv = b_buf[idx];
    float x  = av + dt_bias[h];
    float sp = (x > 20.f) ? x : log1pf(__expf(x));
    glog[idx] = -__expf(A_log[h]) * sp;
    beta[idx] = 1.f / (1.f + __expf(-bv));
}

// ===================================================================
// Two-pass chunked gated delta rule (unchanged).
// ===================================================================

// shared strides
constexpr int RSK  = 136;   // 128-wide bf16 rows (128 data + 8 pad)
constexpr int RST  = 72;    // 64-wide bf16 rows (64 data + 8 pad)
constexpr int RSTD = 68;    // pass-1 X^T rows (64 data + 4 pad)
constexpr int RSR1 = 260;   // pass-1 RHS f32 rows (256 data + 4 pad)
constexpr int RSR2 = 132;   // pass-2 U f32 rows (128 data + 4 pad)

// ---- pass-1 LDS layout ----
constexpr int P1_oKs  = 0;                       // 64*136*2 = 17408
constexpr int P1_oQs  = P1_oKs + 64 * RSK * 2;   // 17408
constexpr int P1_oDT  = 0;                       // overlay Ks+Qs: 256*68*2 = 34816
constexpr int P1_oAf  = P1_oQs + 64 * RSK * 2;   // 34816 (64*72*2 = 9216)
constexpr int P1_oRHS = P1_oAf + 64 * RST * 2;   // 44032 (64*260*4 = 66560)
constexpr int P1_oG   = P1_oRHS + 64 * RSR1 * 4; // 110592
constexpr int P1_oEG  = P1_oG + 256;
constexpr int P1_oBs  = P1_oEG + 256;
constexpr int P1_SMEM = P1_oBs + 256;            // 111616

__global__ __launch_bounds__(256, 1) void chunk_prep(
    unsigned short* __restrict__ qkv,     // v-slot overwritten with Wkn
    const float* __restrict__ glog,
    const float* __restrict__ beta,
    float* __restrict__ Ubuf,
    unsigned short* __restrict__ Wqkbuf)
{
    extern __shared__ __align__(16) char smem[];
    unsigned short* sKs = (unsigned short*)(smem + P1_oKs);
    unsigned short* sQs = (unsigned short*)(smem + P1_oQs);
    unsigned short* sDT = (unsigned short*)(smem + P1_oDT);
    unsigned short* sAf = (unsigned short*)(smem + P1_oAf);
    float* sRHS = (float*)(smem + P1_oRHS);
    float* sG   = (float*)(smem + P1_oG);
    float* sEG  = (float*)(smem + P1_oEG);
    float* sBs  = (float*)(smem + P1_oBs);

    const int bid = blockIdx.x;
    const int ch = bid & (NCHUNK - 1);
    const int h  = (bid >> 5) & (HV - 1);
    const int bb = bid >> 10;
    const int hk = h >> 1;
    const int t    = threadIdx.x;
    const int w    = t >> 6;
    const int lane = t & 63;
    const int quad = lane >> 4;
    const int l16  = lane & 15;
    const int quad8 = quad * 8;
    const size_t bL = (size_t)bb * L;
    const int l0 = ch * CHUNK;
    const int VOFF = 2 * KEY_DIM + h * DV;

    // ---- loads ----
    {
        const int r  = t >> 2;
        const int c0 = (t & 3) * 32;
        const unsigned short* grow = qkv + (bL + l0 + r) * CONV_DIM;
        const unsigned short* gq = grow + hk * DK + c0;
        const unsigned short* gk = grow + KEY_DIM + hk * DK + c0;
#pragma unroll
        for (int u = 0; u < 4; ++u) {
            *(uint4*)&sKs[r * RSK + c0 + 8 * u] = *(const uint4*)(gk + 8 * u);
            *(uint4*)&sQs[r * RSK + c0 + 8 * u] = *(const uint4*)(gq + 8 * u);
        }
        if (t < 64) {
            float gl = glog[(bL + l0 + t) * HV + h];
#pragma unroll
            for (int off = 1; off < 64; off <<= 1) {
                float v = __shfl_up(gl, off, 64);
                if (lane >= off) gl += v;
            }
            sG[t]  = gl;
            sEG[t] = __expf(gl);
            sBs[t] = beta[(bL + l0 + t) * HV + h];
        }
    }
    __syncthreads();

    // ---- A = K K^T, Wqk = Q K^T (wave w: cols j in [16w,16w+16)) ----
    {
        ffrag accA[4], accW[4];
#pragma unroll
        for (int mt = 0; mt < 4; ++mt) { accA[mt] = (ffrag)0.f; accW[mt] = (ffrag)0.f; }
#pragma unroll
        for (int kk = 0; kk < 4; ++kk) {
            bfrag bf = *(const bfrag*)&sKs[(16 * w + l16) * RSK + 32 * kk + quad8];
#pragma unroll
            for (int mt = 0; mt < 4; ++mt) {
                bfrag ak = *(const bfrag*)&sKs[(16 * mt + l16) * RSK + 32 * kk + quad8];
                bfrag aq = *(const bfrag*)&sQs[(16 * mt + l16) * RSK + 32 * kk + quad8];
                accA[mt] = __builtin_amdgcn_mfma_f32_16x16x32_bf16(ak, bf, accA[mt], 0, 0, 0);
                accW[mt] = __builtin_amdgcn_mfma_f32_16x16x32_bf16(aq, bf, accW[mt], 0, 0, 0);
            }
        }
        const int j = 16 * w + l16;
        const float gj = sG[j];
        unsigned short* Wqp = Wqkbuf + (size_t)bid * (CHUNK * CHUNK);
#pragma unroll
        for (int mt = 0; mt < 4; ++mt)
#pragma unroll
            for (int reg = 0; reg < 4; ++reg) {
                int i = 16 * mt + quad * 4 + reg;
                float sc = __expf(sG[i] - gj);
                sAf[i * RST + j] = f2bf((j < i) ? sBs[i] * sc * accA[mt][reg] : 0.f);
                Wqp[i * CHUNK + j] = f2bf((j <= i) ? sc * accW[mt][reg] : 0.f);
            }
    }

    // ---- RHS = [ B*V | B*eG*K ] (f32) ----
    {
        const int r  = t >> 2;
        const int c0 = (t & 3) * 32;
        const float be  = sBs[r];
        const float beg = be * sEG[r];
        const unsigned short* gv = qkv + (bL + l0 + r) * CONV_DIM + VOFF + c0;
#pragma unroll
        for (int u = 0; u < 4; ++u) {
            uint4 vv = *(const uint4*)(gv + 8 * u);
            const unsigned short* vp = (const unsigned short*)&vv;
#pragma unroll
            for (int e = 0; e < 8; ++e)
                sRHS[r * RSR1 + c0 + 8 * u + e] = be * bf2f(vp[e]);
        }
#pragma unroll
        for (int u = 0; u < 4; ++u)
#pragma unroll
            for (int e = 0; e < 8; ++e)
                sRHS[r * RSR1 + 128 + c0 + 8 * u + e] =
                    beg * bf2f(sKs[r * RSK + c0 + 8 * u + e]);
    }
    __syncthreads();   // Ks/Qs reads done -> DT overlay writable

    // zero X^T staging (padding rows read by block-solve MFMAs)
    for (int u = t; u < 256 * RSTD / 2; u += 256) ((uint32_t*)sDT)[u] = 0;

    // ---- blocked forward substitution, 256 columns ----
    float* Up = Ubuf + (size_t)bid * (CHUNK * DV);
    for (int sb = 0; sb < 4; ++sb) {
        const int sb16 = 16 * sb;
        if (sb > 0) {
            const int kbn = (sb + 1) >> 1;
            ffrag c16[4];
#pragma unroll
            for (int nt = 0; nt < 4; ++nt) c16[nt] = (ffrag)0.f;
            for (int kb = 0; kb < kbn; ++kb) {
                bfrag af = *(const bfrag*)&sAf[(sb16 + l16) * RST + 32 * kb + quad8];
#pragma unroll
                for (int nt = 0; nt < 4; ++nt) {
                    bfrag bf = *(const bfrag*)&sDT[(64 * w + 16 * nt + l16) * RSTD + 32 * kb + quad8];
                    c16[nt] = __builtin_amdgcn_mfma_f32_16x16x32_bf16(af, bf, c16[nt], 0, 0, 0);
                }
            }
#pragma unroll
            for (int nt = 0; nt < 4; ++nt)
#pragma unroll
                for (int reg = 0; reg < 4; ++reg)
                    sRHS[(sb16 + quad * 4 + reg) * RSR1 + 64 * w + 16 * nt + l16] -= c16[nt][reg];
        }
        __syncthreads();
        {   // serial 16x16 unit-lower solve; thread t owns column t
            const int c = t;
            float d16[16];
#pragma unroll
            for (int e = 0; e < 16; ++e) {
                const int i = sb16 + e;
                float acc = sRHS[i * RSR1 + c];
#pragma unroll
                for (int f = 0; f < 16; ++f)
                    if (f < e) acc -= bf2f(sAf[i * RST + sb16 + f]) * d16[f];
                d16[e] = acc;
            }
#pragma unroll
            for (int e = 0; e < 16; e += 2)
                *(uint32_t*)&sDT[c * RSTD + sb16 + e] = pk2(d16[e], d16[e + 1]);
            if (c < 128) {
                float* up = Up + c;
#pragma unroll
                for (int e = 0; e < 16; ++e) up[(size_t)(sb16 + e) * DV] = d16[e];
            } else {
                unsigned short* wp = qkv + (bL + l0 + sb16) * CONV_DIM + VOFF + (c - 128);
#pragma unroll
                for (int e = 0; e < 16; ++e) wp[(size_t)e * CONV_DIM] = f2bf(-d16[e]);
            }
        }
        __syncthreads();
    }
}

// ---- pass-2 LDS layout ----
constexpr int P2_oSTb = 0;                         // 128*136*2 = 34816
constexpr int P2_oWk  = P2_oSTb + 128 * RSK * 2;   // 34816 (+17408)
constexpr int P2_oQs  = P2_oWk + 64 * RSK * 2;     // 52224 (+17408)
constexpr int P2_oKT  = P2_oQs + 64 * RSK * 2;     // 69632 (+18432)
constexpr int P2_oWqk = P2_oKT + 128 * RST * 2;    // 88064 (+9216)
constexpr int P2_oDT  = P2_oWqk + 64 * RST * 2;    // 97280 (+18432)
constexpr int P2_oDdT = P2_oDT + 128 * RST * 2;    // 115712 (+18432) -> 134144
constexpr int P2_oU   = P2_oDT;                    // overlay DT+DdT (64*132*4 = 33792 <= 36864)
constexpr int P2_oEG  = P2_oDdT + 128 * RST * 2;   // 134144
constexpr int P2_oEGd = P2_oEG + 256;              // 134400
constexpr int P2_oNW  = P2_oEGd + 256;             // 134656
constexpr int P2_SMEM = P2_oNW + 512;              // 135168

__global__ __launch_bounds__(256, 1) void chunk_scan2(
    const unsigned short* __restrict__ qkv,   // q,k raw; v-slot holds Wkn
    const float* __restrict__ glog,
    const float* __restrict__ Ubuf,
    const unsigned short* __restrict__ Wqkbuf,
    unsigned short* __restrict__ z_io,
    const float* __restrict__ norm_w)
{
    extern __shared__ __align__(16) char smem[];
    unsigned short* sSTb = (unsigned short*)(smem + P2_oSTb);
    unsigned short* sWk  = (unsigned short*)(smem + P2_oWk);
    unsigned short* sQs  = (unsigned short*)(smem + P2_oQs);
    unsigned short* sKT  = (unsigned short*)(smem + P2_oKT);
    unsigned short* sWqk = (unsigned short*)(smem + P2_oWqk);
    unsigned short* sDT  = (unsigned short*)(smem + P2_oDT);
    unsigned short* sDdT = (unsigned short*)(smem + P2_oDdT);
    float* sU   = (float*)(smem + P2_oU);
    float* sEG  = (float*)(smem + P2_oEG);
    float* sEGd = (float*)(smem + P2_oEGd);
    float* sNW  = (float*)(smem + P2_oNW);

    const int bb = blockIdx.x >> 5;
    const int h  = blockIdx.x & (HV - 1);
    const int hk = h >> 1;
    const int t    = threadIdx.x;
    const int w    = t >> 6;
    const int lane = t & 63;
    const int quad = lane >> 4;
    const int l16  = lane & 15;
    const int quad8 = quad * 8;
    const size_t bL = (size_t)bb * L;
    const int VOFF = 2 * KEY_DIM + h * DV;
    const size_t chbase0 = ((size_t)bb * HV + h) * NCHUNK;

    // persistent state: ST[dv][dk], wave w owns dv in [32w,32w+32)
    ffrag accS[2][8];
#pragma unroll
    for (int mt = 0; mt < 2; ++mt)
#pragma unroll
        for (int nt = 0; nt < 8; ++nt) accS[mt][nt] = (ffrag)0.f;

    for (int u = t; u < 64 * RSK; u += 256) ((uint32_t*)sSTb)[u] = 0;  // 128*136 bf16
    if (t < 128) sNW[t] = norm_w[t];

    for (int ch = 0; ch < NCHUNK; ++ch) {
        const int l0 = ch * CHUNK;
        const size_t cb = chbase0 + ch;
        __syncthreads();   // A: prev STb written; all prev-phase LDS reads done

        // ---- load phase ----
        {
            const int r  = t >> 2;
            const int c0 = (t & 3) * 32;
            const unsigned short* grow = qkv + (bL + l0 + r) * CONV_DIM;
            const unsigned short* gq = grow + hk * DK + c0;
            const unsigned short* gk = grow + KEY_DIM + hk * DK + c0;
            const unsigned short* gw = grow + VOFF + c0;
#pragma unroll
            for (int u = 0; u < 4; ++u) {
                uint4 kv = *(const uint4*)(gk + 8 * u);
                *(uint4*)&sQs[r * RSK + c0 + 8 * u] = *(const uint4*)(gq + 8 * u);
                *(uint4*)&sWk[r * RSK + c0 + 8 * u] = *(const uint4*)(gw + 8 * u);
                const unsigned short* kp = (const unsigned short*)&kv;
#pragma unroll
                for (int e = 0; e < 8; ++e)
                    sKT[(c0 + 8 * u + e) * RST + r] = kp[e];
            }
            const float* up = Ubuf + cb * (CHUNK * DV) + r * DV + c0;
#pragma unroll
            for (int u = 0; u < 8; ++u)
                *(float4*)&sU[r * RSR2 + c0 + 4 * u] = *(const float4*)(up + 4 * u);
            const int cw = (t & 3) * 16;
            const unsigned short* qp = Wqkbuf + cb * (CHUNK * CHUNK) + r * CHUNK + cw;
#pragma unroll
            for (int u = 0; u < 2; ++u)
                *(uint4*)&sWqk[r * RST + cw + 8 * u] = *(const uint4*)(qp + 8 * u);
            if (t < 64) {
                float gl = glog[(bL + l0 + t) * HV + h];
#pragma unroll
                for (int off = 1; off < 64; off <<= 1) {
                    float v = __shfl_up(gl, off, 64);
                    if (lane >= off) gl += v;
                }
                float gc = __shfl(gl, 63, 64);
                sEG[t]  = __expf(gl);
                sEGd[t] = __expf(gc - gl);
            }
        }
        __syncthreads();   // B

        // ---- Delta = U + Wkn . ST (wave w: dv in [32w,32w+32)) ----
        ffrag accD[4][2];
#pragma unroll
        for (int mt = 0; mt < 4; ++mt)
#pragma unroll
            for (int nt = 0; nt < 2; ++nt)
#pragma unroll
                for (int reg = 0; reg < 4; ++reg)
                    accD[mt][nt][reg] =
                        sU[(16 * mt + quad * 4 + reg) * RSR2 + 32 * w + 16 * nt + l16];
#pragma unroll
        for (int kk = 0; kk < 4; ++kk) {
            bfrag b0 = *(const bfrag*)&sSTb[(32 * w + l16) * RSK + 32 * kk + quad8];
            bfrag b1 = *(const bfrag*)&sSTb[(32 * w + 16 + l16) * RSK + 32 * kk + quad8];
#pragma unroll
            for (int mt = 0; mt < 4; ++mt) {
                bfrag af = *(const bfrag*)&sWk[(16 * mt + l16) * RSK + 32 * kk + quad8];
                accD[mt][0] = __builtin_amdgcn_mfma_f32_16x16x32_bf16(af, b0, accD[mt][0], 0, 0, 0);
                accD[mt][1] = __builtin_amdgcn_mfma_f32_16x16x32_bf16(af, b1, accD[mt][1], 0, 0, 0);
            }
        }
        __syncthreads();   // C: sU reads done -> DT/DdT overlay writable

        // ---- write Delta^T and decayed Delta^T ----
#pragma unroll
        for (int mt = 0; mt < 4; ++mt)
#pragma unroll
            for (int nt = 0; nt < 2; ++nt) {
                const int dv = 32 * w + 16 * nt + l16;
#pragma unroll
                for (int reg = 0; reg < 4; ++reg) {
                    const int i = 16 * mt + quad * 4 + reg;
                    float d = accD[mt][nt][reg];
                    sDT[dv * RST + i]  = f2bf(d);
                    sDdT[dv * RST + i] = f2bf(d * sEGd[i]);
                }
            }
        __syncthreads();   // D

        // ---- O = eG*(Q ST) + Wqk . Delta ; epilogue ; state update ----
        {
            ffrag accO[8];
#pragma unroll
            for (int nt = 0; nt < 8; ++nt) accO[nt] = (ffrag)0.f;
#pragma unroll
            for (int kk = 0; kk < 4; ++kk) {
                bfrag af = *(const bfrag*)&sQs[(16 * w + l16) * RSK + 32 * kk + quad8];
#pragma unroll
                for (int nt = 0; nt < 8; ++nt) {
                    bfrag bf = *(const bfrag*)&sSTb[(16 * nt + l16) * RSK + 32 * kk + quad8];
                    accO[nt] = __builtin_amdgcn_mfma_f32_16x16x32_bf16(af, bf, accO[nt], 0, 0, 0);
                }
            }
#pragma unroll
            for (int nt = 0; nt < 8; ++nt)
#pragma unroll
                for (int reg = 0; reg < 4; ++reg)
                    accO[nt][reg] *= sEG[16 * w + quad * 4 + reg];
#pragma unroll
            for (int kk = 0; kk < 2; ++kk) {
                bfrag af = *(const bfrag*)&sWqk[(16 * w + l16) * RST + 32 * kk + quad8];
#pragma unroll
                for (int nt = 0; nt < 8; ++nt) {
                    bfrag bf = *(const bfrag*)&sDT[(16 * nt + l16) * RST + 32 * kk + quad8];
                    accO[nt] = __builtin_amdgcn_mfma_f32_16x16x32_bf16(af, bf, accO[nt], 0, 0, 0);
                }
            }
            // RMSNorm over dv + silu(z) gate, write y over z
            float inv[4];
#pragma unroll
            for (int reg = 0; reg < 4; ++reg) {
                float p = 0.f;
#pragma unroll
                for (int nt = 0; nt < 8; ++nt) p += accO[nt][reg] * accO[nt][reg];
#pragma unroll
                for (int m = 1; m < 16; m <<= 1) p += __shfl_xor(p, m, 64);
                inv[reg] = rsqrtf(p * (1.f / 128.f) + EPS);
            }
            const int i0 = 16 * w + quad * 4;
#pragma unroll
            for (int nt = 0; nt < 8; ++nt) {
                const int dv = 16 * nt + l16;
                const float nwv = sNW[dv];
#pragma unroll
                for (int reg = 0; reg < 4; ++reg) {
                    size_t zi = (bL + l0 + i0 + reg) * (size_t)VAL_DIM + h * DV + dv;
                    float zv = bf2f(z_io[zi]);
                    float y = accO[nt][reg] * inv[reg] * nwv * (zv / (1.f + __expf(-zv)));
                    z_io[zi] = f2bf(y);
                }
            }

            // state update: ST = eGc*ST + DdT . KT
            const float eGc = sEG[63];
#pragma unroll
            for (int mt = 0; mt < 2; ++mt)
#pragma unroll
                for (int nt = 0; nt < 8; ++nt)
#pragma unroll
                    for (int reg = 0; reg < 4; ++reg) accS[mt][nt][reg] *= eGc;
#pragma unroll
            for (int kk = 0; kk < 2; ++kk) {
                bfrag a0 = *(const bfrag*)&sDdT[(32 * w + l16) * RST + 32 * kk + quad8];
                bfrag a1 = *(const bfrag*)&sDdT[(32 * w + 16 + l16) * RST + 32 * kk + quad8];
#pragma unroll
                for (int nt = 0; nt < 8; ++nt) {
                    bfrag bk = *(const bfrag*)&sKT[(16 * nt + l16) * RST + 32 * kk + quad8];
                    accS[0][nt] = __builtin_amdgcn_mfma_f32_16x16x32_bf16(a0, bk, accS[0][nt], 0, 0, 0);
                    accS[1][nt] = __builtin_amdgcn_mfma_f32_16x16x32_bf16(a1, bk, accS[1][nt], 0, 0, 0);
                }
            }
        }
        __syncthreads();   // E: all STb/DT/DdT/KT reads done

        // ---- materialize STb (bf16) for next chunk ----
#pragma unroll
        for (int mt = 0; mt < 2; ++mt)
#pragma unroll
            for (int nt = 0; nt < 8; ++nt)
#pragma unroll
                for (int reg = 0; reg < 4; ++reg)
                    sSTb[(32 * w + 16 * mt + quad * 4 + reg) * RSK + 16 * nt + l16] =
                        f2bf(accS[mt][nt][reg]);
    }
}

// ---------------- launch ----------------
extern "C" void kernel_launch(void* const* d_in, const int* in_sizes, int n_in,
                              void* d_out, int out_size, void* d_ws, size_t ws_size,
                              hipStream_t stream)
{
    const float* x        = (const float*)d_in[0];
    const float* W_qkv    = (const float*)d_in[1];
    const float* W_z      = (const float*)d_in[2];
    const float* W_a      = (const float*)d_in[3];
    const float* W_b      = (const float*)d_in[4];
    const float* conv_w   = (const float*)d_in[5];
    const float* A_log    = (const float*)d_in[6];
    const float* dt_bias  = (const float*)d_in[7];
    const float* norm_w   = (const float*)d_in[8];
    const float* W_out    = (const float*)d_in[9];
    float* out = (float*)d_out;
    char*  ws  = (char*)d_ws;

    if (ws_size < WS_NEED_BYTES) return;

    unsigned short* qkv = (unsigned short*)(ws + OFF_QKV);
    unsigned short* z   = (unsigned short*)(ws + OFF_Z);
    float* a    = (float*)(ws + OFF_A);
    float* bbuf = (float*)(ws + OFF_B);
    float* gl   = (float*)(ws + OFF_G);
    float* beta = (float*)(ws + OFF_BETA);
    float* Ubuf = (float*)(ws + OFF_U);
    unsigned short* Wqkbuf = (unsigned short*)(ws + OFF_WQK);
    unsigned short* Wcat   = (unsigned short*)(ws + OFF_WCAT);  // overlay on U
    unsigned short* xb     = (unsigned short*)(ws + OFF_XB);    // overlay on Wqk
    unsigned short* Wob    = (unsigned short*)(ws + OFF_WOB);   // overlay on U

    static bool attr_set = false;
    if (!attr_set) {
        (void)hipFuncSetAttribute((const void*)chunk_prep,
                                  hipFuncAttributeMaxDynamicSharedMemorySize, P1_SMEM);
        (void)hipFuncSetAttribute((const void*)chunk_scan2,
                                  hipFuncAttributeMaxDynamicSharedMemorySize, P2_SMEM);
        (void)hipFuncSetAttribute((const void*)gemm_inproj_bf,
                                  hipFuncAttributeMaxDynamicSharedMemorySize, 131072);
        attr_set = true;
    }

    // 0. pre-convert operands to bf16 (Wcat overlays U-region, xb overlays Wqk-region)
    cvt_wcat<<<NPAD, 256, 0, stream>>>(W_qkv, W_z, W_a, W_b, Wcat);
    cvt_f32bf<<<(int)ROWS, 256, 0, stream>>>(x, xb, DIM);
    // 1. fused input projections (bf16 MFMA GEMM, 256^2 dbuf)
    gemm_inproj_bf<<<(NPAD / 256) * 16, 512, 131072, stream>>>(xb, Wcat, qkv, z, a, bbuf);
    // 2. depthwise causal conv + silu
    conv_silu<<<(B * CONV_DIM) / 256, 256, 0, stream>>>(qkv, conv_w);
    // 3. l2norm q,k heads
    normqk<<<(B * L * 2 * HK) / 4, 256, 0, stream>>>(qkv);
    // 4. gate coefficients (log-space g)
    gatecoef<<<(B * L * HV) / 256, 256, 0, stream>>>(a, bbuf, A_log, dt_bias, gl, beta);
    // 5a. parallel chunk prep: A, Wqk, solve -> U (f32, overwrites Wcat), Wkn (v-slot)
    chunk_prep<<<NCH_TOT, 256, P1_SMEM, stream>>>(qkv, gl, beta, Ubuf, Wqkbuf);
    // 5b. sequential scan: Delta/O/state + fused gated RMSNorm (y overwrites z)
    chunk_scan2<<<B * HV, 256, P2_SMEM, stream>>>(qkv, gl, Ubuf, Wqkbuf, z, norm_w);
    // 5c. convert W_out to bf16 (U dead now; overlay)
    cvt_f32bf<<<DIM, 256, 0, stream>>>(W_out, Wob, VAL_DIM);
    // 6. output projection (bf16 MFMA GEMM, 128^2 dbuf)
    gemm_outproj_bf<<<(ROWS / 128) * (DIM / 128), 256, 0, stream>>>(z, Wob, out);
}

// Round 4
// 989.837 us; speedup vs baseline: 1.1375x; 1.1375x over previous
//
#include <hip/hip_runtime.h>
#include <hip/hip_bf16.h>
#include <cstddef>
#include <cstdint>

// ---------------- problem constants ----------------
constexpr int B = 2, L = 2048, DIM = 2048;
constexpr int HK = 16, HV = 32, DK = 128, DV = 128;
constexpr int KEY_DIM = HK * DK;                    // 2048
constexpr int VAL_DIM = HV * DV;                    // 4096
constexpr int CONV_DIM = 2 * KEY_DIM + VAL_DIM;     // 8192
constexpr int NPROJ = CONV_DIM + VAL_DIM + HV + HV; // 12352
constexpr int NPAD  = ((NPROJ + 255) / 256) * 256;  // 12544 (256-tileable)
constexpr size_t ROWS = (size_t)B * L;              // 4096
constexpr float EPS = 1e-6f;
constexpr int CHUNK = 64, NCHUNK = L / CHUNK;       // 32 chunks
constexpr int NCH_TOT = B * HV * NCHUNK;            // 2048 chunk-head blocks
constexpr int CONV_LT = 8;                          // conv L-tiles
constexpr int CONV_TL = L / CONV_LT;                // 256

// workspace layout (BYTE offsets). Total ~188 MB (bf16 staging overlaid).
constexpr size_t OFF_QKV  = 0;                                   // bf16
constexpr size_t OFF_Z    = OFF_QKV + ROWS * CONV_DIM * 2;       // bf16 (y in-place)
constexpr size_t OFF_A    = OFF_Z   + ROWS * VAL_DIM * 2;        // f32
constexpr size_t OFF_B    = OFF_A   + ROWS * HV * 4;
constexpr size_t OFF_G    = OFF_B   + ROWS * HV * 4;             // g (log-space)
constexpr size_t OFF_BETA = OFF_G   + ROWS * HV * 4;
constexpr size_t OFF_U    = OFF_BETA + ROWS * HV * 4;            // f32 U = T(BV)
constexpr size_t OFF_WQK  = OFF_U + (size_t)NCH_TOT * CHUNK * DV * 4;  // bf16 Wqk
constexpr size_t OFF_HALO = OFF_WQK + (size_t)NCH_TOT * CHUNK * CHUNK * 2; // conv halos
constexpr size_t WS_NEED_BYTES = OFF_HALO + (size_t)3 * B * CONV_LT * CONV_DIM * 2;
// overlays (lifetime-disjoint):
constexpr size_t OFF_WCAT = OFF_U;    // Wcat bf16 (NPAD x DIM) until inproj done
constexpr size_t OFF_XB   = OFF_WQK;  // x bf16 until inproj done
constexpr size_t OFF_WOB  = OFF_U;    // Wout bf16 after chunk_scan2
static_assert((size_t)NPAD * DIM * 2 <= (size_t)NCH_TOT * CHUNK * DV * 4, "Wcat fits U");

// ---------------- bf16 helpers ----------------
__device__ __forceinline__ float bf2f(unsigned short u) {
    union { float f; uint32_t i; } c; c.i = ((uint32_t)u) << 16; return c.f;
}
__device__ __forceinline__ unsigned short f2bf(float f) {
    union { float f; uint32_t u; } c; c.f = f;
    uint32_t u = c.u + 0x7FFFu + ((c.u >> 16) & 1u);   // RTNE
    return (unsigned short)(u >> 16);
}
__device__ __forceinline__ uint32_t pk2(float a, float b) {
    return (uint32_t)f2bf(a) | ((uint32_t)f2bf(b) << 16);
}

// MFMA fragment types (16x16x32 bf16)
typedef __attribute__((ext_vector_type(8))) short bfrag;   // 8 bf16
typedef __attribute__((ext_vector_type(4))) float ffrag;   // 4 f32

// async global->LDS, 16B per lane (dest is wave-uniform base + lane*16)
__device__ __forceinline__ void gload16(const unsigned short* g, unsigned short* l) {
    __builtin_amdgcn_global_load_lds(
        (const __attribute__((address_space(1))) uint32_t*)g,
        (__attribute__((address_space(3))) uint32_t*)l, 16, 0, 0);
}

// ================= f32 -> bf16 conversion kernels =================
__device__ __forceinline__ const float* w_row_multi(int n, const float* Wq, const float* Wz,
                                                    const float* Wa, const float* Wb) {
    if (n < CONV_DIM)                return Wq + (size_t)n * DIM;
    if (n < CONV_DIM + VAL_DIM)      return Wz + (size_t)(n - CONV_DIM) * DIM;
    if (n < CONV_DIM + VAL_DIM + HV) return Wa + (size_t)(n - CONV_DIM - VAL_DIM) * DIM;
    return Wb + (size_t)(n - CONV_DIM - VAL_DIM - HV) * DIM;
}

__global__ __launch_bounds__(256) void cvt_wcat(
    const float* __restrict__ Wq, const float* __restrict__ Wz,
    const float* __restrict__ Wa, const float* __restrict__ Wb,
    unsigned short* __restrict__ dst)
{
    const int r = blockIdx.x;            // 0..NPAD-1
    const int c = threadIdx.x * 8;       // 256*8 = 2048 = DIM
    uint4 o;
    if (r < NPROJ) {
        const float* s = w_row_multi(r, Wq, Wz, Wa, Wb) + c;
        float4 v0 = *(const float4*)s;
        float4 v1 = *(const float4*)(s + 4);
        o = make_uint4(pk2(v0.x, v0.y), pk2(v0.z, v0.w), pk2(v1.x, v1.y), pk2(v1.z, v1.w));
    } else {
        o = make_uint4(0u, 0u, 0u, 0u);
    }
    *(uint4*)&dst[(size_t)r * DIM + c] = o;
}

__global__ __launch_bounds__(256) void cvt_f32bf(const float* __restrict__ src,
                                                 unsigned short* __restrict__ dst, int cols)
{
    const size_t r = blockIdx.x;
    for (int c = threadIdx.x * 8; c < cols; c += 256 * 8) {
        const float* s = src + r * cols + c;
        float4 v0 = *(const float4*)s;
        float4 v1 = *(const float4*)(s + 4);
        *(uint4*)&dst[r * cols + c] =
            make_uint4(pk2(v0.x, v0.y), pk2(v0.z, v0.w), pk2(v1.x, v1.y), pk2(v1.z, v1.w));
    }
}

// ================= shared GEMM epilogue helper (inproj) =================
__device__ __forceinline__ void store_multi(int m, int n, float v,
                                            unsigned short* qkv, unsigned short* z,
                                            float* a, float* b) {
    if (n < CONV_DIM) {
        qkv[(size_t)m * CONV_DIM + n] = f2bf(v);
    } else if (n < CONV_DIM + VAL_DIM) {
        z[(size_t)m * VAL_DIM + (n - CONV_DIM)] = f2bf(v);
    } else if (n < CONV_DIM + VAL_DIM + HV) {
        a[(size_t)m * HV + (n - CONV_DIM - VAL_DIM)] = v;
    } else if (n < NPROJ) {
        b[(size_t)m * HV + (n - CONV_DIM - VAL_DIM - HV)] = v;
    }
}

constexpr int BK = 64;

// ===================================================================
// 256^2-tile double-buffered inproj GEMM (unchanged from round 3).
// ===================================================================
__global__ __launch_bounds__(512, 2) void gemm_inproj_bf(
    const unsigned short* __restrict__ xb,     // (ROWS, DIM)
    const unsigned short* __restrict__ Wcat,   // (NPAD, DIM), pad rows zero
    unsigned short* __restrict__ qkv, unsigned short* __restrict__ z,
    float* __restrict__ a_out, float* __restrict__ b_out)
{
    extern __shared__ __align__(16) unsigned short lds[];   // 131072 B

    constexpr int NBX = NPAD / 256;            // 49 col panels
    constexpr int NB  = NBX * 16;              // 784 blocks
    const int id  = blockIdx.x;
    const int swz = (id & 7) * (NB >> 3) + (id >> 3);
    const int bx  = swz >> 4;
    const int by  = swz & 15;
    const int row0 = by * 256;
    const int col0 = bx * 256;

    const int t = threadIdx.x, lane = t & 63, wid = t >> 6;
    const int wr = wid >> 2, wc = wid & 3;
    const int quad = lane >> 4, l16 = lane & 15;

    ffrag acc[8][4];
#pragma unroll
    for (int i = 0; i < 8; ++i)
#pragma unroll
        for (int j = 0; j < 4; ++j) acc[i][j] = (ffrag)0.f;

    const int srow  = t >> 3;
    const int sslot = t & 7;
    const int scol  = ((sslot ^ (srow & 7)) * 8);
    const unsigned short* aS = xb   + (size_t)(row0 + srow) * DIM + scol;
    const unsigned short* bS = Wcat + (size_t)(col0 + srow) * DIM + scol;
    unsigned short* aD0 = lds + (wid * 8) * 64;
    unsigned short* bD0 = lds + 32768 + (wid * 8) * 64;

    const int x7 = l16 & 7;

    auto STAGE = [&](int buf, int k0) {
        unsigned short* aD = aD0 + buf * 16384;
        unsigned short* bD = bD0 + buf * 16384;
#pragma unroll
        for (int j = 0; j < 4; ++j) {
            gload16(aS + (size_t)(j * 64) * DIM + k0, aD + j * 64 * 64);
            gload16(bS + (size_t)(j * 64) * DIM + k0, bD + j * 64 * 64);
        }
    };

    auto COMPUTE = [&](int buf) {
        const unsigned short* A  = lds + buf * 16384;
        const unsigned short* Bm = lds + 32768 + buf * 16384;
#pragma unroll
        for (int kk = 0; kk < 2; ++kk) {
            const int so = ((kk * 4 + quad) ^ x7) * 8;
            bfrag aF[8], bF[4];
#pragma unroll
            for (int m = 0; m < 8; ++m)
                aF[m] = *(const bfrag*)&A[(wr * 128 + m * 16 + l16) * 64 + so];
#pragma unroll
            for (int n = 0; n < 4; ++n)
                bF[n] = *(const bfrag*)&Bm[(wc * 64 + n * 16 + l16) * 64 + so];
#pragma unroll
            for (int m = 0; m < 8; ++m)
#pragma unroll
                for (int n = 0; n < 4; ++n)
                    acc[m][n] = __builtin_amdgcn_mfma_f32_16x16x32_bf16(
                        aF[m], bF[n], acc[m][n], 0, 0, 0);
        }
    };

    STAGE(0, 0);
    __syncthreads();
    for (int kt = 0; kt < DIM / BK; ++kt) {
        if (kt + 1 < DIM / BK) STAGE((kt + 1) & 1, (kt + 1) * BK);
        COMPUTE(kt & 1);
        __syncthreads();
    }

#pragma unroll
    for (int m = 0; m < 8; ++m)
#pragma unroll
        for (int n = 0; n < 4; ++n) {
            int gr = row0 + wr * 128 + m * 16 + quad * 4;
            int gc = col0 + wc * 64 + n * 16 + l16;
#pragma unroll
            for (int reg = 0; reg < 4; ++reg)
                store_multi(gr + reg, gc, acc[m][n][reg], qkv, z, a_out, b_out);
        }
}

// ===================================================================
// 128^2-tile double-buffered outproj GEMM (unchanged from round 3).
// ===================================================================
__global__ __launch_bounds__(256) void gemm_outproj_bf(
    const unsigned short* __restrict__ A,    // (ROWS, VAL_DIM)
    const unsigned short* __restrict__ Wb,   // (DIM, VAL_DIM)
    float* __restrict__ C)                   // (ROWS, DIM)
{
    __shared__ __align__(16) unsigned short As[2][128 * BK];
    __shared__ __align__(16) unsigned short Bs[2][128 * BK];

    constexpr int NB = (ROWS / 128) * (DIM / 128);   // 512
    const int id  = blockIdx.x;
    const int swz = (id & 7) * (NB >> 3) + (id >> 3);
    const int bx  = swz >> 5;
    const int by  = swz & 31;
    const int row0 = by * 128;
    const int col0 = bx * 128;

    const int t = threadIdx.x, lane = t & 63, wid = t >> 6;
    const int quad = lane >> 4, l16 = lane & 15;
    const int wm = (wid >> 1) * 64, wn = (wid & 1) * 64;

    ffrag acc[4][4];
#pragma unroll
    for (int i = 0; i < 4; ++i)
#pragma unroll
        for (int j = 0; j < 4; ++j) acc[i][j] = (ffrag)0.f;

    const int srow  = t >> 3;
    const int sslot = t & 7;
    const int scol  = ((sslot ^ (srow & 7)) * 8);
    const unsigned short* aS = A  + (size_t)(row0 + srow) * VAL_DIM + scol;
    const unsigned short* bS = Wb + (size_t)(col0 + srow) * VAL_DIM + scol;

    const int aBase = (wm + l16) * BK;
    const int bBase = (wn + l16) * BK;
    const int x7 = l16 & 7;

    auto STAGE = [&](int buf, int k0) {
        unsigned short* aD = &As[buf][(wid * 8) * 64];
        unsigned short* bD = &Bs[buf][(wid * 8) * 64];
#pragma unroll
        for (int j = 0; j < 4; ++j) {
            gload16(aS + (size_t)(j * 32) * VAL_DIM + k0, aD + j * 32 * 64);
            gload16(bS + (size_t)(j * 32) * VAL_DIM + k0, bD + j * 32 * 64);
        }
    };

    auto COMPUTE = [&](int buf) {
#pragma unroll
        for (int kk = 0; kk < 2; ++kk) {
            const int so = ((kk * 4 + quad) ^ x7) * 8;
            bfrag aF[4], bF[4];
#pragma unroll
            for (int mt = 0; mt < 4; ++mt) aF[mt] = *(const bfrag*)&As[buf][aBase + mt * 16 * BK + so];
#pragma unroll
            for (int nt = 0; nt < 4; ++nt) bF[nt] = *(const bfrag*)&Bs[buf][bBase + nt * 16 * BK + so];
#pragma unroll
            for (int mt = 0; mt < 4; ++mt)
#pragma unroll
                for (int nt = 0; nt < 4; ++nt)
                    acc[mt][nt] = __builtin_amdgcn_mfma_f32_16x16x32_bf16(
                        aF[mt], bF[nt], acc[mt][nt], 0, 0, 0);
        }
    };

    STAGE(0, 0);
    __syncthreads();
    for (int kt = 0; kt < VAL_DIM / BK; ++kt) {
        if (kt + 1 < VAL_DIM / BK) STAGE((kt + 1) & 1, (kt + 1) * BK);
        COMPUTE(kt & 1);
        __syncthreads();
    }

#pragma unroll
    for (int mt = 0; mt < 4; ++mt)
#pragma unroll
        for (int nt = 0; nt < 4; ++nt) {
            int gr = row0 + wm + mt * 16 + quad * 4;
            int gc = col0 + wn + nt * 16 + l16;
#pragma unroll
            for (int reg = 0; reg < 4; ++reg)
                C[(size_t)(gr + reg) * DIM + gc] = acc[mt][nt][reg];
        }
}

// ================= conv halo snapshot (race-free tiling) =================
// Saves the 3 input values left of each L-tile boundary BEFORE the in-place
// conv overwrites them (cross-block read-after-write is dispatch-ordered).
__global__ __launch_bounds__(256) void conv_halo(const unsigned short* __restrict__ qkv,
                                                 unsigned short* __restrict__ hbuf)
{
    int idx = blockIdx.x * 256 + threadIdx.x;     // B * CONV_LT * CONV_DIM
    int c    = idx & (CONV_DIM - 1);
    int tile = (idx >> 13) & (CONV_LT - 1);
    int b    = idx >> 16;
    int l0 = tile * CONV_TL;
    const unsigned short* p = qkv + (size_t)b * L * CONV_DIM + c;
#pragma unroll
    for (int j = 0; j < 3; ++j) {
        unsigned short v = (tile > 0) ? p[(size_t)(l0 - 3 + j) * CONV_DIM] : (unsigned short)0;
        hbuf[((size_t)j * B * CONV_LT + b * CONV_LT + tile) * CONV_DIM + c] = v;
    }
}

// ================= depthwise causal conv1d + SiLU (L-tiled) =================
__global__ __launch_bounds__(256) void conv_silu(unsigned short* __restrict__ qkv,
                                                 const float* __restrict__ conv_w,
                                                 const unsigned short* __restrict__ hbuf)
{
    int idx = blockIdx.x * 256 + threadIdx.x;     // B * CONV_LT * CONV_DIM
    int c    = idx & (CONV_DIM - 1);
    int tile = (idx >> 13) & (CONV_LT - 1);
    int b    = idx >> 16;
    const float w0 = conv_w[c * 4 + 0];
    const float w1 = conv_w[c * 4 + 1];
    const float w2 = conv_w[c * 4 + 2];
    const float w3 = conv_w[c * 4 + 3];
    unsigned short* p = qkv + ((size_t)b * L + tile * CONV_TL) * CONV_DIM + c;
    const size_t hb = (size_t)b * CONV_LT + tile;
    float x0 = bf2f(hbuf[((size_t)0 * B * CONV_LT + hb) * CONV_DIM + c]);
    float x1 = bf2f(hbuf[((size_t)1 * B * CONV_LT + hb) * CONV_DIM + c]);
    float x2 = bf2f(hbuf[((size_t)2 * B * CONV_LT + hb) * CONV_DIM + c]);
    for (int l0 = 0; l0 < CONV_TL; l0 += 8) {
        float xv[8];
#pragma unroll
        for (int j = 0; j < 8; ++j) xv[j] = bf2f(p[(size_t)(l0 + j) * CONV_DIM]);
#pragma unroll
        for (int j = 0; j < 8; ++j) {
            float h = w0 * x0 + w1 * x1 + w2 * x2 + w3 * xv[j];
            float s = h / (1.f + __expf(-h));
            p[(size_t)(l0 + j) * CONV_DIM] = f2bf(s);
            x0 = x1; x1 = x2; x2 = xv[j];
        }
    }
}

// ================= l2norm of q,k heads =================
__global__ __launch_bounds__(256) void normqk(unsigned short* __restrict__ qkv)
{
    int wid  = blockIdx.x * 4 + (threadIdx.x >> 6);
    int lane = threadIdx.x & 63;
    int hk  = wid & 15;
    int sel = (wid >> 4) & 1;
    int row = wid >> 5;
    unsigned short* p = qkv + (size_t)row * CONV_DIM + sel * KEY_DIM + hk * DK;
    float x0 = bf2f(p[lane]), x1 = bf2f(p[lane + 64]);
    float ss = x0 * x0 + x1 * x1;
#pragma unroll
    for (int o = 32; o >= 1; o >>= 1) ss += __shfl_xor(ss, o);
    float sc = rsqrtf(ss + 1e-6f);
    if (sel == 0) sc *= 0.08838834764831845f;   // DK^-0.5
    p[lane]      = f2bf(x0 * sc);
    p[lane + 64] = f2bf(x1 * sc);
}

// ================= gate coefficients: g (log) and beta =================
__global__ __launch_bounds__(256) void gatecoef(const float* __restrict__ a_buf,
                                                const float* __restrict__ b_buf,
                                                const float* __restrict__ A_log,
                                                const float* __restrict__ dt_bias,
                                                float* __restrict__ glog,
                                                float* __restrict__ beta)
{
    int idx = blockIdx.x * blockDim.x + threadIdx.x;
    int h = idx & (HV - 1);
    float av = a_buf[idx];
    float bv = b_buf[idx];
    float x  = av + dt_bias[h];
    float sp = (x > 20.f) ? x : log1pf(__expf(x));
    glog[idx] = -__expf(A_log[h]) * sp;
    beta[idx] = 1.f / (1.f + __expf(-bv));
}

// ===================================================================
// Two-pass chunked gated delta rule.
// ===================================================================

// shared strides
constexpr int RSK  = 136;   // 128-wide bf16 rows (128 data + 8 pad)
constexpr int RST  = 72;    // 64-wide bf16 rows (64 data + 8 pad)
constexpr int RSTD = 68;    // pass-1 X^T rows (64 data + 4 pad)
constexpr int RSR1 = 260;   // pass-1 RHS f32 rows (256 data + 4 pad)

// ---- pass-1 LDS layout ----
constexpr int P1_oKs  = 0;                       // 64*136*2 = 17408
constexpr int P1_oQs  = P1_oKs + 64 * RSK * 2;   // 17408
constexpr int P1_oDT  = 0;                       // overlay Ks+Qs: 256*68*2 = 34816
constexpr int P1_oAf  = P1_oQs + 64 * RSK * 2;   // 34816 (64*72*2 = 9216)
constexpr int P1_oRHS = P1_oAf + 64 * RST * 2;   // 44032 (64*260*4 = 66560)
constexpr int P1_oG   = P1_oRHS + 64 * RSR1 * 4; // 110592
constexpr int P1_oEG  = P1_oG + 256;
constexpr int P1_oBs  = P1_oEG + 256;
constexpr int P1_SMEM = P1_oBs + 256;            // 111616

__global__ __launch_bounds__(256, 1) void chunk_prep(
    unsigned short* __restrict__ qkv,     // v-slot overwritten with Wkn
    const float* __restrict__ glog,
    const float* __restrict__ beta,
    float* __restrict__ Ubuf,
    unsigned short* __restrict__ Wqkbuf)
{
    extern __shared__ __align__(16) char smem[];
    unsigned short* sKs = (unsigned short*)(smem + P1_oKs);
    unsigned short* sQs = (unsigned short*)(smem + P1_oQs);
    unsigned short* sDT = (unsigned short*)(smem + P1_oDT);
    unsigned short* sAf = (unsigned short*)(smem + P1_oAf);
    float* sRHS = (float*)(smem + P1_oRHS);
    float* sG   = (float*)(smem + P1_oG);
    float* sEG  = (float*)(smem + P1_oEG);
    float* sBs  = (float*)(smem + P1_oBs);

    const int bid = blockIdx.x;
    const int ch = bid & (NCHUNK - 1);
    const int h  = (bid >> 5) & (HV - 1);
    const int bb = bid >> 10;
    const int hk = h >> 1;
    const int t    = threadIdx.x;
    const int w    = t >> 6;
    const int lane = t & 63;
    const int quad = lane >> 4;
    const int l16  = lane & 15;
    const int quad8 = quad * 8;
    const size_t bL = (size_t)bb * L;
    const int l0 = ch * CHUNK;
    const int VOFF = 2 * KEY_DIM + h * DV;

    // ---- loads ----
    {
        const int r  = t >> 2;
        const int c0 = (t & 3) * 32;
        const unsigned short* grow = qkv + (bL + l0 + r) * CONV_DIM;
        const unsigned short* gq = grow + hk * DK + c0;
        const unsigned short* gk = grow + KEY_DIM + hk * DK + c0;
#pragma unroll
        for (int u = 0; u < 4; ++u) {
            *(uint4*)&sKs[r * RSK + c0 + 8 * u] = *(const uint4*)(gk + 8 * u);
            *(uint4*)&sQs[r * RSK + c0 + 8 * u] = *(const uint4*)(gq + 8 * u);
        }
        if (t < 64) {
            float gl = glog[(bL + l0 + t) * HV + h];
#pragma unroll
            for (int off = 1; off < 64; off <<= 1) {
                float v = __shfl_up(gl, off, 64);
                if (lane >= off) gl += v;
            }
            sG[t]  = gl;
            sEG[t] = __expf(gl);
            sBs[t] = beta[(bL + l0 + t) * HV + h];
        }
    }
    __syncthreads();

    // ---- A = K K^T, Wqk = Q K^T (wave w: cols j in [16w,16w+16)) ----
    {
        ffrag accA[4], accW[4];
#pragma unroll
        for (int mt = 0; mt < 4; ++mt) { accA[mt] = (ffrag)0.f; accW[mt] = (ffrag)0.f; }
#pragma unroll
        for (int kk = 0; kk < 4; ++kk) {
            bfrag bf = *(const bfrag*)&sKs[(16 * w + l16) * RSK + 32 * kk + quad8];
#pragma unroll
            for (int mt = 0; mt < 4; ++mt) {
                bfrag ak = *(const bfrag*)&sKs[(16 * mt + l16) * RSK + 32 * kk + quad8];
                bfrag aq = *(const bfrag*)&sQs[(16 * mt + l16) * RSK + 32 * kk + quad8];
                accA[mt] = __builtin_amdgcn_mfma_f32_16x16x32_bf16(ak, bf, accA[mt], 0, 0, 0);
                accW[mt] = __builtin_amdgcn_mfma_f32_16x16x32_bf16(aq, bf, accW[mt], 0, 0, 0);
            }
        }
        const int j = 16 * w + l16;
        const float gj = sG[j];
        unsigned short* Wqp = Wqkbuf + (size_t)bid * (CHUNK * CHUNK);
#pragma unroll
        for (int mt = 0; mt < 4; ++mt)
#pragma unroll
            for (int reg = 0; reg < 4; ++reg) {
                int i = 16 * mt + quad * 4 + reg;
                float sc = __expf(sG[i] - gj);
                sAf[i * RST + j] = f2bf((j < i) ? sBs[i] * sc * accA[mt][reg] : 0.f);
                Wqp[i * CHUNK + j] = f2bf((j <= i) ? sc * accW[mt][reg] : 0.f);
            }
    }

    // ---- RHS = [ B*V | B*eG*K ] (f32) ----
    {
        const int r  = t >> 2;
        const int c0 = (t & 3) * 32;
        const float be  = sBs[r];
        const float beg = be * sEG[r];
        const unsigned short* gv = qkv + (bL + l0 + r) * CONV_DIM + VOFF + c0;
#pragma unroll
        for (int u = 0; u < 4; ++u) {
            uint4 vv = *(const uint4*)(gv + 8 * u);
            const unsigned short* vp = (const unsigned short*)&vv;
#pragma unroll
            for (int e = 0; e < 8; ++e)
                sRHS[r * RSR1 + c0 + 8 * u + e] = be * bf2f(vp[e]);
        }
#pragma unroll
        for (int u = 0; u < 4; ++u)
#pragma unroll
            for (int e = 0; e < 8; ++e)
                sRHS[r * RSR1 + 128 + c0 + 8 * u + e] =
                    beg * bf2f(sKs[r * RSK + c0 + 8 * u + e]);
    }
    __syncthreads();   // Ks/Qs reads done -> DT overlay writable

    // zero X^T staging (padding rows read by block-solve MFMAs)
    for (int u = t; u < 256 * RSTD / 2; u += 256) ((uint32_t*)sDT)[u] = 0;

    // ---- blocked forward substitution, 256 columns ----
    float* Up = Ubuf + (size_t)bid * (CHUNK * DV);
    for (int sb = 0; sb < 4; ++sb) {
        const int sb16 = 16 * sb;
        if (sb > 0) {
            const int kbn = (sb + 1) >> 1;
            ffrag c16[4];
#pragma unroll
            for (int nt = 0; nt < 4; ++nt) c16[nt] = (ffrag)0.f;
            for (int kb = 0; kb < kbn; ++kb) {
                bfrag af = *(const bfrag*)&sAf[(sb16 + l16) * RST + 32 * kb + quad8];
#pragma unroll
                for (int nt = 0; nt < 4; ++nt) {
                    bfrag bf = *(const bfrag*)&sDT[(64 * w + 16 * nt + l16) * RSTD + 32 * kb + quad8];
                    c16[nt] = __builtin_amdgcn_mfma_f32_16x16x32_bf16(af, bf, c16[nt], 0, 0, 0);
                }
            }
#pragma unroll
            for (int nt = 0; nt < 4; ++nt)
#pragma unroll
                for (int reg = 0; reg < 4; ++reg)
                    sRHS[(sb16 + quad * 4 + reg) * RSR1 + 64 * w + 16 * nt + l16] -= c16[nt][reg];
        }
        __syncthreads();
        {   // serial 16x16 unit-lower solve; thread t owns column t
            const int c = t;
            float d16[16];
#pragma unroll
            for (int e = 0; e < 16; ++e) {
                const int i = sb16 + e;
                float acc = sRHS[i * RSR1 + c];
#pragma unroll
                for (int f = 0; f < 16; ++f)
                    if (f < e) acc -= bf2f(sAf[i * RST + sb16 + f]) * d16[f];
                d16[e] = acc;
            }
#pragma unroll
            for (int e = 0; e < 16; e += 2)
                *(uint32_t*)&sDT[c * RSTD + sb16 + e] = pk2(d16[e], d16[e + 1]);
            if (c < 128) {
                float* up = Up + c;
#pragma unroll
                for (int e = 0; e < 16; ++e) up[(size_t)(sb16 + e) * DV] = d16[e];
            } else {
                unsigned short* wp = qkv + (bL + l0 + sb16) * CONV_DIM + VOFF + (c - 128);
#pragma unroll
                for (int e = 0; e < 16; ++e) wp[(size_t)e * CONV_DIM] = f2bf(-d16[e]);
            }
        }
        __syncthreads();
    }
}

// ---- pass-2 LDS layout (sU removed; KT XOR-swizzled) ----
constexpr int P2_oSTb = 0;                         // 128*136*2 = 34816
constexpr int P2_oWk  = P2_oSTb + 128 * RSK * 2;   // +17408
constexpr int P2_oQs  = P2_oWk + 64 * RSK * 2;     // +17408
constexpr int P2_oKT  = P2_oQs + 64 * RSK * 2;     // +18432
constexpr int P2_oWqk = P2_oKT + 128 * RST * 2;    // +9216
constexpr int P2_oDT  = P2_oWqk + 64 * RST * 2;    // +18432
constexpr int P2_oDdT = P2_oDT + 128 * RST * 2;    // +18432
constexpr int P2_oEG  = P2_oDdT + 128 * RST * 2;   // 134144
constexpr int P2_oEGd = P2_oEG + 256;              // 134400
constexpr int P2_oNW  = P2_oEGd + 256;             // 134656
constexpr int P2_SMEM = P2_oNW + 512;              // 135168

__global__ __launch_bounds__(256, 1) void chunk_scan2(
    const unsigned short* __restrict__ qkv,   // q,k raw; v-slot holds Wkn
    const float* __restrict__ glog,
    const float* __restrict__ Ubuf,
    const unsigned short* __restrict__ Wqkbuf,
    unsigned short* __restrict__ z_io,
    const float* __restrict__ norm_w)
{
    extern __shared__ __align__(16) char smem[];
    unsigned short* sSTb = (unsigned short*)(smem + P2_oSTb);
    unsigned short* sWk  = (unsigned short*)(smem + P2_oWk);
    unsigned short* sQs  = (unsigned short*)(smem + P2_oQs);
    unsigned short* sKT  = (unsigned short*)(smem + P2_oKT);
    unsigned short* sWqk = (unsigned short*)(smem + P2_oWqk);
    unsigned short* sDT  = (unsigned short*)(smem + P2_oDT);
    unsigned short* sDdT = (unsigned short*)(smem + P2_oDdT);
    float* sEG  = (float*)(smem + P2_oEG);
    float* sEGd = (float*)(smem + P2_oEGd);
    float* sNW  = (float*)(smem + P2_oNW);

    const int bb = blockIdx.x >> 5;
    const int h  = blockIdx.x & (HV - 1);
    const int hk = h >> 1;
    const int t    = threadIdx.x;
    const int w    = t >> 6;
    const int lane = t & 63;
    const int quad = lane >> 4;
    const int l16  = lane & 15;
    const int quad8 = quad * 8;
    const size_t bL = (size_t)bb * L;
    const int VOFF = 2 * KEY_DIM + h * DV;
    const size_t chbase0 = ((size_t)bb * HV + h) * NCHUNK;

    const int r  = t >> 2;        // staging row 0..63
    const int c0 = (t & 3) * 32;  // staging col
    const int cw = (t & 3) * 16;

    // persistent state: ST[dv][dk], wave w owns dv in [32w,32w+32)
    ffrag accS[2][8];
#pragma unroll
    for (int mt = 0; mt < 2; ++mt)
#pragma unroll
        for (int nt = 0; nt < 8; ++nt) accS[mt][nt] = (ffrag)0.f;

    for (int u = t; u < 64 * RSK; u += 256) ((uint32_t*)sSTb)[u] = 0;  // 128*136 bf16
    if (t < 128) sNW[t] = norm_w[t];

    // prefetch registers (T14: issue-early / write-late)
    uint4 pQ[4], pK[4], pWk[4], pWqk2[2];
    float pGl;

    auto PF = [&](int ch) {
        const int l0p = ch * CHUNK;
        const unsigned short* grow = qkv + (bL + l0p + r) * CONV_DIM;
        const unsigned short* gq = grow + hk * DK + c0;
        const unsigned short* gk = grow + KEY_DIM + hk * DK + c0;
        const unsigned short* gw = grow + VOFF + c0;
#pragma unroll
        for (int u = 0; u < 4; ++u) {
            pQ[u]  = *(const uint4*)(gq + 8 * u);
            pK[u]  = *(const uint4*)(gk + 8 * u);
            pWk[u] = *(const uint4*)(gw + 8 * u);
        }
        const unsigned short* qp = Wqkbuf + (chbase0 + ch) * (CHUNK * CHUNK) + r * CHUNK + cw;
        pWqk2[0] = *(const uint4*)qp;
        pWqk2[1] = *(const uint4*)(qp + 8);
        pGl = glog[(bL + l0p + (t & 63)) * HV + h];
    };

    PF(0);

    for (int ch = 0; ch < NCHUNK; ++ch) {
        const int l0 = ch * CHUNK;
        const size_t cb = chbase0 + ch;
        __syncthreads();   // A: prev STb written; all prev-phase LDS reads done

        // ---- U -> accD direct from global (latency hides under stage+B) ----
        ffrag accD[4][2];
        {
            const float* up = Ubuf + cb * (CHUNK * DV) + (size_t)(quad * 4) * DV + 32 * w + l16;
#pragma unroll
            for (int mt = 0; mt < 4; ++mt)
#pragma unroll
                for (int nt = 0; nt < 2; ++nt)
#pragma unroll
                    for (int reg = 0; reg < 4; ++reg)
                        accD[mt][nt][reg] = up[(size_t)(16 * mt + reg) * DV + 16 * nt];
        }
        // ---- z gate prefetch (consumed in epilogue) ----
        unsigned short pz[8][4];
        {
            const unsigned short* zp =
                z_io + (bL + l0 + 16 * w + quad * 4) * (size_t)VAL_DIM + h * DV + l16;
#pragma unroll
            for (int nt = 0; nt < 8; ++nt)
#pragma unroll
                for (int reg = 0; reg < 4; ++reg)
                    pz[nt][reg] = zp[(size_t)reg * VAL_DIM + 16 * nt];
        }

        // ---- stage LDS from prefetch regs ----
#pragma unroll
        for (int u = 0; u < 4; ++u) {
            *(uint4*)&sQs[r * RSK + c0 + 8 * u] = pQ[u];
            *(uint4*)&sWk[r * RSK + c0 + 8 * u] = pWk[u];
            const unsigned short* kp = (const unsigned short*)&pK[u];
#pragma unroll
            for (int e = 0; e < 8; ++e) {
                const int c = c0 + 8 * u + e;
                sKT[c * RST + ((((r >> 3) ^ (c >> 3)) & 7) << 3) + (r & 7)] = kp[e];
            }
        }
        *(uint4*)&sWqk[r * RST + cw]     = pWqk2[0];
        *(uint4*)&sWqk[r * RST + cw + 8] = pWqk2[1];

        // gates (cumulative log-decay scan)
        {
            float gl = pGl;
            if (t < 64) {
#pragma unroll
                for (int off = 1; off < 64; off <<= 1) {
                    float v = __shfl_up(gl, off, 64);
                    if (lane >= off) gl += v;
                }
                float gc = __shfl(gl, 63, 64);
                sEG[t]  = __expf(gl);
                sEGd[t] = __expf(gc - gl);
            }
        }

        if (ch + 1 < NCHUNK) PF(ch + 1);   // next-chunk loads fly across compute
        __syncthreads();   // B

        // ---- Delta = U + Wkn . ST (wave w: dv in [32w,32w+32)) ----
#pragma unroll
        for (int kk = 0; kk < 4; ++kk) {
            bfrag b0 = *(const bfrag*)&sSTb[(32 * w + l16) * RSK + 32 * kk + quad8];
            bfrag b1 = *(const bfrag*)&sSTb[(32 * w + 16 + l16) * RSK + 32 * kk + quad8];
#pragma unroll
            for (int mt = 0; mt < 4; ++mt) {
                bfrag af = *(const bfrag*)&sWk[(16 * mt + l16) * RSK + 32 * kk + quad8];
                accD[mt][0] = __builtin_amdgcn_mfma_f32_16x16x32_bf16(af, b0, accD[mt][0], 0, 0, 0);
                accD[mt][1] = __builtin_amdgcn_mfma_f32_16x16x32_bf16(af, b1, accD[mt][1], 0, 0, 0);
            }
        }

        // ---- packed Delta^T / decayed Delta^T writes (register-dependent) ----
#pragma unroll
        for (int mt = 0; mt < 4; ++mt) {
            const int i0 = 16 * mt + quad * 4;
            const float e0 = sEGd[i0], e1 = sEGd[i0 + 1], e2 = sEGd[i0 + 2], e3 = sEGd[i0 + 3];
#pragma unroll
            for (int nt = 0; nt < 2; ++nt) {
                const int dv = 32 * w + 16 * nt + l16;
                const float d0 = accD[mt][nt][0], d1 = accD[mt][nt][1];
                const float d2 = accD[mt][nt][2], d3 = accD[mt][nt][3];
                *(uint32_t*)&sDT[dv * RST + i0]      = pk2(d0, d1);
                *(uint32_t*)&sDT[dv * RST + i0 + 2]  = pk2(d2, d3);
                *(uint32_t*)&sDdT[dv * RST + i0]     = pk2(d0 * e0, d1 * e1);
                *(uint32_t*)&sDdT[dv * RST + i0 + 2] = pk2(d2 * e2, d3 * e3);
            }
        }
        __syncthreads();   // D

        // ---- O = eG*(Q ST) + Wqk . Delta ; epilogue ; state update ----
        {
            ffrag accO[8];
#pragma unroll
            for (int nt = 0; nt < 8; ++nt) accO[nt] = (ffrag)0.f;
#pragma unroll
            for (int kk = 0; kk < 4; ++kk) {
                bfrag af = *(const bfrag*)&sQs[(16 * w + l16) * RSK + 32 * kk + quad8];
#pragma unroll
                for (int nt = 0; nt < 8; ++nt) {
                    bfrag bf = *(const bfrag*)&sSTb[(16 * nt + l16) * RSK + 32 * kk + quad8];
                    accO[nt] = __builtin_amdgcn_mfma_f32_16x16x32_bf16(af, bf, accO[nt], 0, 0, 0);
                }
            }
#pragma unroll
            for (int nt = 0; nt < 8; ++nt)
#pragma unroll
                for (int reg = 0; reg < 4; ++reg)
                    accO[nt][reg] *= sEG[16 * w + quad * 4 + reg];
#pragma unroll
            for (int kk = 0; kk < 2; ++kk) {
                bfrag af = *(const bfrag*)&sWqk[(16 * w + l16) * RST + 32 * kk + quad8];
#pragma unroll
                for (int nt = 0; nt < 8; ++nt) {
                    bfrag bf = *(const bfrag*)&sDT[(16 * nt + l16) * RST + 32 * kk + quad8];
                    accO[nt] = __builtin_amdgcn_mfma_f32_16x16x32_bf16(af, bf, accO[nt], 0, 0, 0);
                }
            }
            // RMSNorm over dv + silu(z) gate, write y over z
            float inv[4];
#pragma unroll
            for (int reg = 0; reg < 4; ++reg) {
                float p = 0.f;
#pragma unroll
                for (int nt = 0; nt < 8; ++nt) p += accO[nt][reg] * accO[nt][reg];
#pragma unroll
                for (int m = 1; m < 16; m <<= 1) p += __shfl_xor(p, m, 64);
                inv[reg] = rsqrtf(p * (1.f / 128.f) + EPS);
            }
            unsigned short* zw =
                z_io + (bL + l0 + 16 * w + quad * 4) * (size_t)VAL_DIM + h * DV + l16;
#pragma unroll
            for (int nt = 0; nt < 8; ++nt) {
                const float nwv = sNW[16 * nt + l16];
#pragma unroll
                for (int reg = 0; reg < 4; ++reg) {
                    float zv = bf2f(pz[nt][reg]);
                    float y = accO[nt][reg] * inv[reg] * nwv * (zv / (1.f + __expf(-zv)));
                    zw[(size_t)reg * VAL_DIM + 16 * nt] = f2bf(y);
                }
            }

            // state update: ST = eGc*ST + DdT . KT (KT XOR-swizzled)
            const float eGc = sEG[63];
#pragma unroll
            for (int mt = 0; mt < 2; ++mt)
#pragma unroll
                for (int nt = 0; nt < 8; ++nt)
#pragma unroll
                    for (int reg = 0; reg < 4; ++reg) accS[mt][nt][reg] *= eGc;
#pragma unroll
            for (int kk = 0; kk < 2; ++kk) {
                bfrag a0 = *(const bfrag*)&sDdT[(32 * w + l16) * RST + 32 * kk + quad8];
                bfrag a1 = *(const bfrag*)&sDdT[(32 * w + 16 + l16) * RST + 32 * kk + quad8];
#pragma unroll
                for (int nt = 0; nt < 8; ++nt) {
                    const int ck = 16 * nt + l16;
                    bfrag bk = *(const bfrag*)&sKT[ck * RST +
                                 ((((4 * kk + quad) ^ (ck >> 3)) & 7) << 3)];
                    accS[0][nt] = __builtin_amdgcn_mfma_f32_16x16x32_bf16(a0, bk, accS[0][nt], 0, 0, 0);
                    accS[1][nt] = __builtin_amdgcn_mfma_f32_16x16x32_bf16(a1, bk, accS[1][nt], 0, 0, 0);
                }
            }
        }
        __syncthreads();   // E: all STb/DT/DdT/KT reads done

        // ---- materialize STb (bf16) for next chunk ----
#pragma unroll
        for (int mt = 0; mt < 2; ++mt)
#pragma unroll
            for (int nt = 0; nt < 8; ++nt)
#pragma unroll
                for (int reg = 0; reg < 4; ++reg)
                    sSTb[(32 * w + 16 * mt + quad * 4 + reg) * RSK + 16 * nt + l16] =
                        f2bf(accS[mt][nt][reg]);
    }
}

// ---------------- launch ----------------
extern "C" void kernel_launch(void* const* d_in, const int* in_sizes, int n_in,
                              void* d_out, int out_size, void* d_ws, size_t ws_size,
                              hipStream_t stream)
{
    const float* x        = (const float*)d_in[0];
    const float* W_qkv    = (const float*)d_in[1];
    const float* W_z      = (const float*)d_in[2];
    const float* W_a      = (const float*)d_in[3];
    const float* W_b      = (const float*)d_in[4];
    const float* conv_w   = (const float*)d_in[5];
    const float* A_log    = (const float*)d_in[6];
    const float* dt_bias  = (const float*)d_in[7];
    const float* norm_w   = (const float*)d_in[8];
    const float* W_out    = (const float*)d_in[9];
    float* out = (float*)d_out;
    char*  ws  = (char*)d_ws;

    if (ws_size < WS_NEED_BYTES) return;

    unsigned short* qkv = (unsigned short*)(ws + OFF_QKV);
    unsigned short* z   = (unsigned short*)(ws + OFF_Z);
    float* a    = (float*)(ws + OFF_A);
    float* bbuf = (float*)(ws + OFF_B);
    float* gl   = (float*)(ws + OFF_G);
    float* beta = (float*)(ws + OFF_BETA);
    float* Ubuf = (float*)(ws + OFF_U);
    unsigned short* Wqkbuf = (unsigned short*)(ws + OFF_WQK);
    unsigned short* hbuf   = (unsigned short*)(ws + OFF_HALO);
    unsigned short* Wcat   = (unsigned short*)(ws + OFF_WCAT);  // overlay on U
    unsigned short* xb     = (unsigned short*)(ws + OFF_XB);    // overlay on Wqk
    unsigned short* Wob    = (unsigned short*)(ws + OFF_WOB);   // overlay on U

    static bool attr_set = false;
    if (!attr_set) {
        (void)hipFuncSetAttribute((const void*)chunk_prep,
                                  hipFuncAttributeMaxDynamicSharedMemorySize, P1_SMEM);
        (void)hipFuncSetAttribute((const void*)chunk_scan2,
                                  hipFuncAttributeMaxDynamicSharedMemorySize, P2_SMEM);
        (void)hipFuncSetAttribute((const void*)gemm_inproj_bf,
                                  hipFuncAttributeMaxDynamicSharedMemorySize, 131072);
        attr_set = true;
    }

    // 0. pre-convert operands to bf16 (Wcat overlays U-region, xb overlays Wqk-region)
    cvt_wcat<<<NPAD, 256, 0, stream>>>(W_qkv, W_z, W_a, W_b, Wcat);
    cvt_f32bf<<<(int)ROWS, 256, 0, stream>>>(x, xb, DIM);
    // 1. fused input projections (bf16 MFMA GEMM, 256^2 dbuf)
    gemm_inproj_bf<<<(NPAD / 256) * 16, 512, 131072, stream>>>(xb, Wcat, qkv, z, a, bbuf);
    // 2. depthwise causal conv + silu (L-tiled, halo snapshot first)
    conv_halo<<<(B * CONV_LT * CONV_DIM) / 256, 256, 0, stream>>>(qkv, hbuf);
    conv_silu<<<(B * CONV_LT * CONV_DIM) / 256, 256, 0, stream>>>(qkv, conv_w, hbuf);
    // 3. l2norm q,k heads
    normqk<<<(B * L * 2 * HK) / 4, 256, 0, stream>>>(qkv);
    // 4. gate coefficients (log-space g)
    gatecoef<<<(B * L * HV) / 256, 256, 0, stream>>>(a, bbuf, A_log, dt_bias, gl, beta);
    // 5a. parallel chunk prep: A, Wqk, solve -> U (f32, overwrites Wcat), Wkn (v-slot)
    chunk_prep<<<NCH_TOT, 256, P1_SMEM, stream>>>(qkv, gl, beta, Ubuf, Wqkbuf);
    // 5b. sequential scan (pipelined): Delta/O/state + fused gated RMSNorm
    chunk_scan2<<<B * HV, 256, P2_SMEM, stream>>>(qkv, gl, Ubuf, Wqkbuf, z, norm_w);
    // 5c. convert W_out to bf16 (U dead now; overlay)
    cvt_f32bf<<<DIM, 256, 0, stream>>>(W_out, Wob, VAL_DIM);
    // 6. output projection (bf16 MFMA GEMM, 128^2 dbuf)
    gemm_outproj_bf<<<(ROWS / 128) * (DIM / 128), 256, 0, stream>>>(z, Wob, out);
}

// Round 6
// 966.299 us; speedup vs baseline: 1.1652x; 1.0244x over previous
//
#include <hip/hip_runtime.h>
#include <hip/hip_bf16.h>
#include <cstddef>
#include <cstdint>

// ---------------- problem constants ----------------
constexpr int B = 2, L = 2048, DIM = 2048;
constexpr int HK = 16, HV = 32, DK = 128, DV = 128;
constexpr int KEY_DIM = HK * DK;                    // 2048
constexpr int VAL_DIM = HV * DV;                    // 4096
constexpr int CONV_DIM = 2 * KEY_DIM + VAL_DIM;     // 8192
constexpr int NPROJ = CONV_DIM + VAL_DIM + HV + HV; // 12352
constexpr int NPAD  = ((NPROJ + 255) / 256) * 256;  // 12544 (256-tileable)
constexpr size_t ROWS = (size_t)B * L;              // 4096
constexpr float EPS = 1e-6f;
constexpr int CHUNK = 64, NCHUNK = L / CHUNK;       // 32 chunks
constexpr int NCH_TOT = B * HV * NCHUNK;            // 2048 chunk-head blocks
constexpr int CONV_LT = 8;                          // conv L-tiles
constexpr int CONV_TL = L / CONV_LT;                // 256

// workspace layout (BYTE offsets). Total ~188 MB (bf16 staging overlaid).
constexpr size_t OFF_QKV  = 0;                                   // bf16
constexpr size_t OFF_Z    = OFF_QKV + ROWS * CONV_DIM * 2;       // bf16 (y in-place)
constexpr size_t OFF_A    = OFF_Z   + ROWS * VAL_DIM * 2;        // f32
constexpr size_t OFF_B    = OFF_A   + ROWS * HV * 4;
constexpr size_t OFF_G    = OFF_B   + ROWS * HV * 4;             // g (log-space)
constexpr size_t OFF_BETA = OFF_G   + ROWS * HV * 4;
constexpr size_t OFF_U    = OFF_BETA + ROWS * HV * 4;            // f32 U = T(BV)
constexpr size_t OFF_WQK  = OFF_U + (size_t)NCH_TOT * CHUNK * DV * 4;  // bf16 Wqk
constexpr size_t OFF_HALO = OFF_WQK + (size_t)NCH_TOT * CHUNK * CHUNK * 2; // conv halos
constexpr size_t WS_NEED_BYTES = OFF_HALO + (size_t)3 * B * CONV_LT * CONV_DIM * 2;
// overlays (lifetime-disjoint):
constexpr size_t OFF_WCAT = OFF_U;    // Wcat bf16 (NPAD x DIM) until inproj done
constexpr size_t OFF_XB   = OFF_WQK;  // x bf16 until inproj done
constexpr size_t OFF_WOB  = OFF_U;    // Wout bf16 after chunk_scan2
static_assert((size_t)NPAD * DIM * 2 <= (size_t)NCH_TOT * CHUNK * DV * 4, "Wcat fits U");

// ---------------- bf16 helpers ----------------
__device__ __forceinline__ float bf2f(unsigned short u) {
    union { float f; uint32_t i; } c; c.i = ((uint32_t)u) << 16; return c.f;
}
__device__ __forceinline__ unsigned short f2bf(float f) {
    union { float f; uint32_t u; } c; c.f = f;
    uint32_t u = c.u + 0x7FFFu + ((c.u >> 16) & 1u);   // RTNE
    return (unsigned short)(u >> 16);
}
__device__ __forceinline__ uint32_t pk2(float a, float b) {
    return (uint32_t)f2bf(a) | ((uint32_t)f2bf(b) << 16);
}

// MFMA fragment types (16x16x32 bf16)
typedef __attribute__((ext_vector_type(8))) short bfrag;   // 8 bf16
typedef __attribute__((ext_vector_type(4))) float ffrag;   // 4 f32

// async global->LDS, 16B per lane (dest is wave-uniform base + lane*16)
__device__ __forceinline__ void gload16(const unsigned short* g, unsigned short* l) {
    __builtin_amdgcn_global_load_lds(
        (const __attribute__((address_space(1))) uint32_t*)g,
        (__attribute__((address_space(3))) uint32_t*)l, 16, 0, 0);
}

// ================= f32 -> bf16 conversion kernels =================
__device__ __forceinline__ const float* w_row_multi(int n, const float* Wq, const float* Wz,
                                                    const float* Wa, const float* Wb) {
    if (n < CONV_DIM)                return Wq + (size_t)n * DIM;
    if (n < CONV_DIM + VAL_DIM)      return Wz + (size_t)(n - CONV_DIM) * DIM;
    if (n < CONV_DIM + VAL_DIM + HV) return Wa + (size_t)(n - CONV_DIM - VAL_DIM) * DIM;
    return Wb + (size_t)(n - CONV_DIM - VAL_DIM - HV) * DIM;
}

__global__ __launch_bounds__(256) void cvt_wcat(
    const float* __restrict__ Wq, const float* __restrict__ Wz,
    const float* __restrict__ Wa, const float* __restrict__ Wb,
    unsigned short* __restrict__ dst)
{
    const int r = blockIdx.x;            // 0..NPAD-1
    const int c = threadIdx.x * 8;       // 256*8 = 2048 = DIM
    uint4 o;
    if (r < NPROJ) {
        const float* s = w_row_multi(r, Wq, Wz, Wa, Wb) + c;
        float4 v0 = *(const float4*)s;
        float4 v1 = *(const float4*)(s + 4);
        o = make_uint4(pk2(v0.x, v0.y), pk2(v0.z, v0.w), pk2(v1.x, v1.y), pk2(v1.z, v1.w));
    } else {
        o = make_uint4(0u, 0u, 0u, 0u);
    }
    *(uint4*)&dst[(size_t)r * DIM + c] = o;
}

__global__ __launch_bounds__(256) void cvt_f32bf(const float* __restrict__ src,
                                                 unsigned short* __restrict__ dst, int cols)
{
    const size_t r = blockIdx.x;
    for (int c = threadIdx.x * 8; c < cols; c += 256 * 8) {
        const float* s = src + r * cols + c;
        float4 v0 = *(const float4*)s;
        float4 v1 = *(const float4*)(s + 4);
        *(uint4*)&dst[r * cols + c] =
            make_uint4(pk2(v0.x, v0.y), pk2(v0.z, v0.w), pk2(v1.x, v1.y), pk2(v1.z, v1.w));
    }
}

// ================= shared GEMM epilogue helper (inproj) =================
__device__ __forceinline__ void store_multi(int m, int n, float v,
                                            unsigned short* qkv, unsigned short* z,
                                            float* a, float* b) {
    if (n < CONV_DIM) {
        qkv[(size_t)m * CONV_DIM + n] = f2bf(v);
    } else if (n < CONV_DIM + VAL_DIM) {
        z[(size_t)m * VAL_DIM + (n - CONV_DIM)] = f2bf(v);
    } else if (n < CONV_DIM + VAL_DIM + HV) {
        a[(size_t)m * HV + (n - CONV_DIM - VAL_DIM)] = v;
    } else if (n < NPROJ) {
        b[(size_t)m * HV + (n - CONV_DIM - VAL_DIM - HV)] = v;
    }
}

constexpr int BK = 64;

// ===================================================================
// 256^2-tile double-buffered inproj GEMM (unchanged).
// ===================================================================
__global__ __launch_bounds__(512, 2) void gemm_inproj_bf(
    const unsigned short* __restrict__ xb,     // (ROWS, DIM)
    const unsigned short* __restrict__ Wcat,   // (NPAD, DIM), pad rows zero
    unsigned short* __restrict__ qkv, unsigned short* __restrict__ z,
    float* __restrict__ a_out, float* __restrict__ b_out)
{
    extern __shared__ __align__(16) unsigned short lds[];   // 131072 B

    constexpr int NBX = NPAD / 256;            // 49 col panels
    constexpr int NB  = NBX * 16;              // 784 blocks
    const int id  = blockIdx.x;
    const int swz = (id & 7) * (NB >> 3) + (id >> 3);
    const int bx  = swz >> 4;
    const int by  = swz & 15;
    const int row0 = by * 256;
    const int col0 = bx * 256;

    const int t = threadIdx.x, lane = t & 63, wid = t >> 6;
    const int wr = wid >> 2, wc = wid & 3;
    const int quad = lane >> 4, l16 = lane & 15;

    ffrag acc[8][4];
#pragma unroll
    for (int i = 0; i < 8; ++i)
#pragma unroll
        for (int j = 0; j < 4; ++j) acc[i][j] = (ffrag)0.f;

    const int srow  = t >> 3;
    const int sslot = t & 7;
    const int scol  = ((sslot ^ (srow & 7)) * 8);
    const unsigned short* aS = xb   + (size_t)(row0 + srow) * DIM + scol;
    const unsigned short* bS = Wcat + (size_t)(col0 + srow) * DIM + scol;
    unsigned short* aD0 = lds + (wid * 8) * 64;
    unsigned short* bD0 = lds + 32768 + (wid * 8) * 64;

    const int x7 = l16 & 7;

    auto STAGE = [&](int buf, int k0) {
        unsigned short* aD = aD0 + buf * 16384;
        unsigned short* bD = bD0 + buf * 16384;
#pragma unroll
        for (int j = 0; j < 4; ++j) {
            gload16(aS + (size_t)(j * 64) * DIM + k0, aD + j * 64 * 64);
            gload16(bS + (size_t)(j * 64) * DIM + k0, bD + j * 64 * 64);
        }
    };

    auto COMPUTE = [&](int buf) {
        const unsigned short* A  = lds + buf * 16384;
        const unsigned short* Bm = lds + 32768 + buf * 16384;
#pragma unroll
        for (int kk = 0; kk < 2; ++kk) {
            const int so = ((kk * 4 + quad) ^ x7) * 8;
            bfrag aF[8], bF[4];
#pragma unroll
            for (int m = 0; m < 8; ++m)
                aF[m] = *(const bfrag*)&A[(wr * 128 + m * 16 + l16) * 64 + so];
#pragma unroll
            for (int n = 0; n < 4; ++n)
                bF[n] = *(const bfrag*)&Bm[(wc * 64 + n * 16 + l16) * 64 + so];
#pragma unroll
            for (int m = 0; m < 8; ++m)
#pragma unroll
                for (int n = 0; n < 4; ++n)
                    acc[m][n] = __builtin_amdgcn_mfma_f32_16x16x32_bf16(
                        aF[m], bF[n], acc[m][n], 0, 0, 0);
        }
    };

    STAGE(0, 0);
    __syncthreads();
    for (int kt = 0; kt < DIM / BK; ++kt) {
        if (kt + 1 < DIM / BK) STAGE((kt + 1) & 1, (kt + 1) * BK);
        COMPUTE(kt & 1);
        __syncthreads();
    }

#pragma unroll
    for (int m = 0; m < 8; ++m)
#pragma unroll
        for (int n = 0; n < 4; ++n) {
            int gr = row0 + wr * 128 + m * 16 + quad * 4;
            int gc = col0 + wc * 64 + n * 16 + l16;
#pragma unroll
            for (int reg = 0; reg < 4; ++reg)
                store_multi(gr + reg, gc, acc[m][n][reg], qkv, z, a_out, b_out);
        }
}

// ===================================================================
// 128^2-tile double-buffered outproj GEMM (unchanged).
// ===================================================================
__global__ __launch_bounds__(256) void gemm_outproj_bf(
    const unsigned short* __restrict__ A,    // (ROWS, VAL_DIM)
    const unsigned short* __restrict__ Wb,   // (DIM, VAL_DIM)
    float* __restrict__ C)                   // (ROWS, DIM)
{
    __shared__ __align__(16) unsigned short As[2][128 * BK];
    __shared__ __align__(16) unsigned short Bs[2][128 * BK];

    constexpr int NB = (ROWS / 128) * (DIM / 128);   // 512
    const int id  = blockIdx.x;
    const int swz = (id & 7) * (NB >> 3) + (id >> 3);
    const int bx  = swz >> 5;
    const int by  = swz & 31;
    const int row0 = by * 128;
    const int col0 = bx * 128;

    const int t = threadIdx.x, lane = t & 63, wid = t >> 6;
    const int quad = lane >> 4, l16 = lane & 15;
    const int wm = (wid >> 1) * 64, wn = (wid & 1) * 64;

    ffrag acc[4][4];
#pragma unroll
    for (int i = 0; i < 4; ++i)
#pragma unroll
        for (int j = 0; j < 4; ++j) acc[i][j] = (ffrag)0.f;

    const int srow  = t >> 3;
    const int sslot = t & 7;
    const int scol  = ((sslot ^ (srow & 7)) * 8);
    const unsigned short* aS = A  + (size_t)(row0 + srow) * VAL_DIM + scol;
    const unsigned short* bS = Wb + (size_t)(col0 + srow) * VAL_DIM + scol;

    const int aBase = (wm + l16) * BK;
    const int bBase = (wn + l16) * BK;
    const int x7 = l16 & 7;

    auto STAGE = [&](int buf, int k0) {
        unsigned short* aD = &As[buf][(wid * 8) * 64];
        unsigned short* bD = &Bs[buf][(wid * 8) * 64];
#pragma unroll
        for (int j = 0; j < 4; ++j) {
            gload16(aS + (size_t)(j * 32) * VAL_DIM + k0, aD + j * 32 * 64);
            gload16(bS + (size_t)(j * 32) * VAL_DIM + k0, bD + j * 32 * 64);
        }
    };

    auto COMPUTE = [&](int buf) {
#pragma unroll
        for (int kk = 0; kk < 2; ++kk) {
            const int so = ((kk * 4 + quad) ^ x7) * 8;
            bfrag aF[4], bF[4];
#pragma unroll
            for (int mt = 0; mt < 4; ++mt) aF[mt] = *(const bfrag*)&As[buf][aBase + mt * 16 * BK + so];
#pragma unroll
            for (int nt = 0; nt < 4; ++nt) bF[nt] = *(const bfrag*)&Bs[buf][bBase + nt * 16 * BK + so];
#pragma unroll
            for (int mt = 0; mt < 4; ++mt)
#pragma unroll
                for (int nt = 0; nt < 4; ++nt)
                    acc[mt][nt] = __builtin_amdgcn_mfma_f32_16x16x32_bf16(
                        aF[mt], bF[nt], acc[mt][nt], 0, 0, 0);
        }
    };

    STAGE(0, 0);
    __syncthreads();
    for (int kt = 0; kt < VAL_DIM / BK; ++kt) {
        if (kt + 1 < VAL_DIM / BK) STAGE((kt + 1) & 1, (kt + 1) * BK);
        COMPUTE(kt & 1);
        __syncthreads();
    }

#pragma unroll
    for (int mt = 0; mt < 4; ++mt)
#pragma unroll
        for (int nt = 0; nt < 4; ++nt) {
            int gr = row0 + wm + mt * 16 + quad * 4;
            int gc = col0 + wn + nt * 16 + l16;
#pragma unroll
            for (int reg = 0; reg < 4; ++reg)
                C[(size_t)(gr + reg) * DIM + gc] = acc[mt][nt][reg];
        }
}

// ================= conv halo snapshot (race-free tiling) =================
__global__ __launch_bounds__(256) void conv_halo(const unsigned short* __restrict__ qkv,
                                                 unsigned short* __restrict__ hbuf)
{
    int idx = blockIdx.x * 256 + threadIdx.x;     // B * CONV_LT * CONV_DIM
    int c    = idx & (CONV_DIM - 1);
    int tile = (idx >> 13) & (CONV_LT - 1);
    int b    = idx >> 16;
    int l0 = tile * CONV_TL;
    const unsigned short* p = qkv + (size_t)b * L * CONV_DIM + c;
#pragma unroll
    for (int j = 0; j < 3; ++j) {
        unsigned short v = (tile > 0) ? p[(size_t)(l0 - 3 + j) * CONV_DIM] : (unsigned short)0;
        hbuf[((size_t)j * B * CONV_LT + b * CONV_LT + tile) * CONV_DIM + c] = v;
    }
}

// ================= depthwise causal conv1d + SiLU (L-tiled) =================
__global__ __launch_bounds__(256) void conv_silu(unsigned short* __restrict__ qkv,
                                                 const float* __restrict__ conv_w,
                                                 const unsigned short* __restrict__ hbuf)
{
    int idx = blockIdx.x * 256 + threadIdx.x;     // B * CONV_LT * CONV_DIM
    int c    = idx & (CONV_DIM - 1);
    int tile = (idx >> 13) & (CONV_LT - 1);
    int b    = idx >> 16;
    const float w0 = conv_w[c * 4 + 0];
    const float w1 = conv_w[c * 4 + 1];
    const float w2 = conv_w[c * 4 + 2];
    const float w3 = conv_w[c * 4 + 3];
    unsigned short* p = qkv + ((size_t)b * L + tile * CONV_TL) * CONV_DIM + c;
    const size_t hb = (size_t)b * CONV_LT + tile;
    float x0 = bf2f(hbuf[((size_t)0 * B * CONV_LT + hb) * CONV_DIM + c]);
    float x1 = bf2f(hbuf[((size_t)1 * B * CONV_LT + hb) * CONV_DIM + c]);
    float x2 = bf2f(hbuf[((size_t)2 * B * CONV_LT + hb) * CONV_DIM + c]);
    for (int l0 = 0; l0 < CONV_TL; l0 += 8) {
        float xv[8];
#pragma unroll
        for (int j = 0; j < 8; ++j) xv[j] = bf2f(p[(size_t)(l0 + j) * CONV_DIM]);
#pragma unroll
        for (int j = 0; j < 8; ++j) {
            float h = w0 * x0 + w1 * x1 + w2 * x2 + w3 * xv[j];
            float s = h / (1.f + __expf(-h));
            p[(size_t)(l0 + j) * CONV_DIM] = f2bf(s);
            x0 = x1; x1 = x2; x2 = xv[j];
        }
    }
}

// ================= l2norm of q,k heads =================
__global__ __launch_bounds__(256) void normqk(unsigned short* __restrict__ qkv)
{
    int wid  = blockIdx.x * 4 + (threadIdx.x >> 6);
    int lane = threadIdx.x & 63;
    int hk  = wid & 15;
    int sel = (wid >> 4) & 1;
    int row = wid >> 5;
    unsigned short* p = qkv + (size_t)row * CONV_DIM + sel * KEY_DIM + hk * DK;
    float x0 = bf2f(p[lane]), x1 = bf2f(p[lane + 64]);
    float ss = x0 * x0 + x1 * x1;
#pragma unroll
    for (int o = 32; o >= 1; o >>= 1) ss += __shfl_xor(ss, o);
    float sc = rsqrtf(ss + 1e-6f);
    if (sel == 0) sc *= 0.08838834764831845f;   // DK^-0.5
    p[lane]      = f2bf(x0 * sc);
    p[lane + 64] = f2bf(x1 * sc);
}

// ================= gate coefficients: g (log) and beta =================
__global__ __launch_bounds__(256) void gatecoef(const float* __restrict__ a_buf,
                                                const float* __restrict__ b_buf,
                                                const float* __restrict__ A_log,
                                                const float* __restrict__ dt_bias,
                                                float* __restrict__ glog,
                                                float* __restrict__ beta)
{
    int idx = blockIdx.x * blockDim.x + threadIdx.x;
    int h = idx & (HV - 1);
    float av = a_buf[idx];
    float bv = b_buf[idx];
    float x  = av + dt_bias[h];
    float sp = (x > 20.f) ? x : log1pf(__expf(x));
    glog[idx] = -__expf(A_log[h]) * sp;
    beta[idx] = 1.f / (1.f + __expf(-bv));
}

// ===================================================================
// Two-pass chunked gated delta rule.
// ===================================================================

// shared strides
constexpr int RSK  = 136;   // 128-wide bf16 rows (128 data + 8 pad)
constexpr int RST  = 72;    // 64-wide bf16 rows (64 data + 8 pad)
constexpr int RSTD = 68;    // pass-1 X^T rows (64 data + 4 pad)
constexpr int RSR1 = 260;   // pass-1 RHS f32 rows (256 data + 4 pad)

// ---- pass-1 LDS layout ----
constexpr int P1_oKs  = 0;                       // 64*136*2 = 17408
constexpr int P1_oQs  = P1_oKs + 64 * RSK * 2;   // 17408
constexpr int P1_oDT  = 0;                       // overlay Ks+Qs: 256*68*2 = 34816
constexpr int P1_oAf  = P1_oQs + 64 * RSK * 2;   // 34816 (64*72*2 = 9216)
constexpr int P1_oRHS = P1_oAf + 64 * RST * 2;   // 44032 (64*260*4 = 66560)
constexpr int P1_oG   = P1_oRHS + 64 * RSR1 * 4; // 110592
constexpr int P1_oEG  = P1_oG + 256;
constexpr int P1_oBs  = P1_oEG + 256;
constexpr int P1_SMEM = P1_oBs + 256;            // 111616

__global__ __launch_bounds__(256, 1) void chunk_prep(
    unsigned short* __restrict__ qkv,     // v-slot overwritten with Wkn
    const float* __restrict__ glog,
    const float* __restrict__ beta,
    float* __restrict__ Ubuf,
    unsigned short* __restrict__ Wqkbuf)
{
    extern __shared__ __align__(16) char smem[];
    unsigned short* sKs = (unsigned short*)(smem + P1_oKs);
    unsigned short* sQs = (unsigned short*)(smem + P1_oQs);
    unsigned short* sDT = (unsigned short*)(smem + P1_oDT);
    unsigned short* sAf = (unsigned short*)(smem + P1_oAf);
    float* sRHS = (float*)(smem + P1_oRHS);
    float* sG   = (float*)(smem + P1_oG);
    float* sEG  = (float*)(smem + P1_oEG);
    float* sBs  = (float*)(smem + P1_oBs);

    const int bid = blockIdx.x;
    const int ch = bid & (NCHUNK - 1);
    const int h  = (bid >> 5) & (HV - 1);
    const int bb = bid >> 10;
    const int hk = h >> 1;
    const int t    = threadIdx.x;
    const int w    = t >> 6;
    const int lane = t & 63;
    const int quad = lane >> 4;
    const int l16  = lane & 15;
    const int quad8 = quad * 8;
    const size_t bL = (size_t)bb * L;
    const int l0 = ch * CHUNK;
    const int VOFF = 2 * KEY_DIM + h * DV;

    // ---- loads ----
    {
        const int r  = t >> 2;
        const int c0 = (t & 3) * 32;
        const unsigned short* grow = qkv + (bL + l0 + r) * CONV_DIM;
        const unsigned short* gq = grow + hk * DK + c0;
        const unsigned short* gk = grow + KEY_DIM + hk * DK + c0;
#pragma unroll
        for (int u = 0; u < 4; ++u) {
            *(uint4*)&sKs[r * RSK + c0 + 8 * u] = *(const uint4*)(gk + 8 * u);
            *(uint4*)&sQs[r * RSK + c0 + 8 * u] = *(const uint4*)(gq + 8 * u);
        }
        if (t < 64) {
            float gl = glog[(bL + l0 + t) * HV + h];
#pragma unroll
            for (int off = 1; off < 64; off <<= 1) {
                float v = __shfl_up(gl, off, 64);
                if (lane >= off) gl += v;
            }
            sG[t]  = gl;
            sEG[t] = __expf(gl);
            sBs[t] = beta[(bL + l0 + t) * HV + h];
        }
    }
    __syncthreads();

    // ---- A = K K^T, Wqk = Q K^T (wave w: cols j in [16w,16w+16)) ----
    {
        ffrag accA[4], accW[4];
#pragma unroll
        for (int mt = 0; mt < 4; ++mt) { accA[mt] = (ffrag)0.f; accW[mt] = (ffrag)0.f; }
#pragma unroll
        for (int kk = 0; kk < 4; ++kk) {
            bfrag bf = *(const bfrag*)&sKs[(16 * w + l16) * RSK + 32 * kk + quad8];
#pragma unroll
            for (int mt = 0; mt < 4; ++mt) {
                bfrag ak = *(const bfrag*)&sKs[(16 * mt + l16) * RSK + 32 * kk + quad8];
                bfrag aq = *(const bfrag*)&sQs[(16 * mt + l16) * RSK + 32 * kk + quad8];
                accA[mt] = __builtin_amdgcn_mfma_f32_16x16x32_bf16(ak, bf, accA[mt], 0, 0, 0);
                accW[mt] = __builtin_amdgcn_mfma_f32_16x16x32_bf16(aq, bf, accW[mt], 0, 0, 0);
            }
        }
        const int j = 16 * w + l16;
        const float gj = sG[j];
        unsigned short* Wqp = Wqkbuf + (size_t)bid * (CHUNK * CHUNK);
#pragma unroll
        for (int mt = 0; mt < 4; ++mt)
#pragma unroll
            for (int reg = 0; reg < 4; ++reg) {
                int i = 16 * mt + quad * 4 + reg;
                float sc = __expf(sG[i] - gj);
                sAf[i * RST + j] = f2bf((j < i) ? sBs[i] * sc * accA[mt][reg] : 0.f);
                Wqp[i * CHUNK + j] = f2bf((j <= i) ? sc * accW[mt][reg] : 0.f);
            }
    }

    // ---- RHS = [ B*V | B*eG*K ] (f32) ----
    {
        const int r  = t >> 2;
        const int c0 = (t & 3) * 32;
        const float be  = sBs[r];
        const float beg = be * sEG[r];
        const unsigned short* gv = qkv + (bL + l0 + r) * CONV_DIM + VOFF + c0;
#pragma unroll
        for (int u = 0; u < 4; ++u) {
            uint4 vv = *(const uint4*)(gv + 8 * u);
            const unsigned short* vp = (const unsigned short*)&vv;
#pragma unroll
            for (int e = 0; e < 8; ++e)
                sRHS[r * RSR1 + c0 + 8 * u + e] = be * bf2f(vp[e]);
        }
#pragma unroll
        for (int u = 0; u < 4; ++u)
#pragma unroll
            for (int e = 0; e < 8; ++e)
                sRHS[r * RSR1 + 128 + c0 + 8 * u + e] =
                    beg * bf2f(sKs[r * RSK + c0 + 8 * u + e]);
    }
    __syncthreads();   // Ks/Qs reads done -> DT overlay writable

    // zero X^T staging (padding rows read by block-solve MFMAs)
    for (int u = t; u < 256 * RSTD / 2; u += 256) ((uint32_t*)sDT)[u] = 0;

    // ---- blocked forward substitution, 256 columns ----
    float* Up = Ubuf + (size_t)bid * (CHUNK * DV);
    for (int sb = 0; sb < 4; ++sb) {
        const int sb16 = 16 * sb;
        if (sb > 0) {
            const int kbn = (sb + 1) >> 1;
            ffrag c16[4];
#pragma unroll
            for (int nt = 0; nt < 4; ++nt) c16[nt] = (ffrag)0.f;
            for (int kb = 0; kb < kbn; ++kb) {
                bfrag af = *(const bfrag*)&sAf[(sb16 + l16) * RST + 32 * kb + quad8];
#pragma unroll
                for (int nt = 0; nt < 4; ++nt) {
                    bfrag bf = *(const bfrag*)&sDT[(64 * w + 16 * nt + l16) * RSTD + 32 * kb + quad8];
                    c16[nt] = __builtin_amdgcn_mfma_f32_16x16x32_bf16(af, bf, c16[nt], 0, 0, 0);
                }
            }
#pragma unroll
            for (int nt = 0; nt < 4; ++nt)
#pragma unroll
                for (int reg = 0; reg < 4; ++reg)
                    sRHS[(sb16 + quad * 4 + reg) * RSR1 + 64 * w + 16 * nt + l16] -= c16[nt][reg];
        }
        __syncthreads();
        {   // serial 16x16 unit-lower solve; thread t owns column t
            const int c = t;
            float d16[16];
#pragma unroll
            for (int e = 0; e < 16; ++e) {
                const int i = sb16 + e;
                float acc = sRHS[i * RSR1 + c];
#pragma unroll
                for (int f = 0; f < 16; ++f)
                    if (f < e) acc -= bf2f(sAf[i * RST + sb16 + f]) * d16[f];
                d16[e] = acc;
            }
#pragma unroll
            for (int e = 0; e < 16; e += 2)
                *(uint32_t*)&sDT[c * RSTD + sb16 + e] = pk2(d16[e], d16[e + 1]);
            if (c < 128) {
                float* up = Up + c;
#pragma unroll
                for (int e = 0; e < 16; ++e) up[(size_t)(sb16 + e) * DV] = d16[e];
            } else {
                unsigned short* wp = qkv + (bL + l0 + sb16) * CONV_DIM + VOFF + (c - 128);
#pragma unroll
                for (int e = 0; e < 16; ++e) wp[(size_t)e * CONV_DIM] = f2bf(-d16[e]);
            }
        }
        __syncthreads();
    }
}

// ---- pass-2 LDS layout (8-wave version) ----
constexpr int P2_oSTb = 0;                         // 128*136*2 = 34816
constexpr int P2_oWk  = P2_oSTb + 128 * RSK * 2;   // +17408
constexpr int P2_oQs  = P2_oWk + 64 * RSK * 2;     // +17408
constexpr int P2_oKT  = P2_oQs + 64 * RSK * 2;     // +18432
constexpr int P2_oWqk = P2_oKT + 128 * RST * 2;    // +9216
constexpr int P2_oDT  = P2_oWqk + 64 * RST * 2;    // +18432
constexpr int P2_oDdT = P2_oDT + 128 * RST * 2;    // +18432
constexpr int P2_oEG  = P2_oDdT + 128 * RST * 2;   // 134144
constexpr int P2_oEGd = P2_oEG + 256;              // 134400
constexpr int P2_oNW  = P2_oEGd + 256;             // 134656
constexpr int P2_oP   = P2_oNW + 512;              // 135168 (wave-pair RMS partials)
constexpr int P2_SMEM = P2_oP + 512;               // 135680

// 512 threads / 8 waves: 2 waves/SIMD for latency hiding; per-wave MFMA halves.
// Wave roles: Delta/DdT/state own dv in [16w,16w+16); O phase: wave pair
// (rg=w>>1 rows, dh=w&1 dv-half); RMSNorm combines pair partials via sP.
__global__ __launch_bounds__(512, 1) void chunk_scan2(
    const unsigned short* __restrict__ qkv,   // q,k raw; v-slot holds Wkn
    const float* __restrict__ glog,
    const float* __restrict__ Ubuf,
    const unsigned short* __restrict__ Wqkbuf,
    unsigned short* __restrict__ z_io,
    const float* __restrict__ norm_w)
{
    extern __shared__ __align__(16) char smem[];
    unsigned short* sSTb = (unsigned short*)(smem + P2_oSTb);
    unsigned short* sWk  = (unsigned short*)(smem + P2_oWk);
    unsigned short* sQs  = (unsigned short*)(smem + P2_oQs);
    unsigned short* sKT  = (unsigned short*)(smem + P2_oKT);
    unsigned short* sWqk = (unsigned short*)(smem + P2_oWqk);
    unsigned short* sDT  = (unsigned short*)(smem + P2_oDT);
    unsigned short* sDdT = (unsigned short*)(smem + P2_oDdT);
    float* sEG  = (float*)(smem + P2_oEG);
    float* sEGd = (float*)(smem + P2_oEGd);
    float* sNW  = (float*)(smem + P2_oNW);
    float* sP   = (float*)(smem + P2_oP);

    const int bb = blockIdx.x >> 5;
    const int h  = blockIdx.x & (HV - 1);
    const int hk = h >> 1;
    const int t    = threadIdx.x;            // 0..511
    const int w    = t >> 6;                 // 0..7
    const int lane = t & 63;
    const int quad = lane >> 4;
    const int l16  = lane & 15;
    const int quad8 = quad * 8;
    const int rg = w >> 1;                   // O-phase row group (rows 16rg..)
    const int dh = w & 1;                    // O-phase dv half
    const size_t bL = (size_t)bb * L;
    const int VOFF = 2 * KEY_DIM + h * DV;
    const size_t chbase0 = ((size_t)bb * HV + h) * NCHUNK;

    const int r  = t >> 3;        // staging row 0..63
    const int c0 = (t & 7) * 16;  // staging col
    const int cw = (t & 7) * 8;   // Wqk col

    // persistent state: ST[dv][dk], wave w owns dv in [16w,16w+16)
    ffrag accS[8];
#pragma unroll
    for (int nt = 0; nt < 8; ++nt) accS[nt] = (ffrag)0.f;

    for (int u = t; u < 64 * RSK; u += 512) ((uint32_t*)sSTb)[u] = 0;  // 128*136 bf16
    if (t < 128) sNW[t] = norm_w[t];

    // prefetch registers (issue-early / write-late)
    uint4 pQ[2], pK[2], pWk[2], pWqk;
    float pGl;

    auto PF = [&](int ch) {
        const int l0p = ch * CHUNK;
        const unsigned short* grow = qkv + (bL + l0p + r) * CONV_DIM;
        const unsigned short* gq = grow + hk * DK + c0;
        const unsigned short* gk = grow + KEY_DIM + hk * DK + c0;
        const unsigned short* gw = grow + VOFF + c0;
#pragma unroll
        for (int u = 0; u < 2; ++u) {
            pQ[u]  = *(const uint4*)(gq + 8 * u);
            pK[u]  = *(const uint4*)(gk + 8 * u);
            pWk[u] = *(const uint4*)(gw + 8 * u);
        }
        pWqk = *(const uint4*)(Wqkbuf + (chbase0 + ch) * (CHUNK * CHUNK) + r * CHUNK + cw);
        pGl = glog[(bL + l0p + (t & 63)) * HV + h];
    };

    PF(0);

    for (int ch = 0; ch < NCHUNK; ++ch) {
        const int l0 = ch * CHUNK;
        const size_t cb = chbase0 + ch;
        __syncthreads();   // A: prev STb written; all prev-phase LDS reads done

        // ---- U -> accD direct from global ----
        ffrag accD[4];
        {
            const float* up = Ubuf + cb * (CHUNK * DV) + (size_t)(quad * 4) * DV + 16 * w + l16;
#pragma unroll
            for (int mt = 0; mt < 4; ++mt)
#pragma unroll
                for (int reg = 0; reg < 4; ++reg)
                    accD[mt][reg] = up[(size_t)(16 * mt + reg) * DV];
        }
        // ---- z gate prefetch (consumed in epilogue; wave-pair layout) ----
        unsigned short pz[4][4];
        {
            const unsigned short* zp =
                z_io + (bL + l0 + 16 * rg + quad * 4) * (size_t)VAL_DIM + h * DV + 64 * dh + l16;
#pragma unroll
            for (int nt = 0; nt < 4; ++nt)
#pragma unroll
                for (int reg = 0; reg < 4; ++reg)
                    pz[nt][reg] = zp[(size_t)reg * VAL_DIM + 16 * nt];
        }

        // ---- stage LDS from prefetch regs ----
#pragma unroll
        for (int u = 0; u < 2; ++u) {
            *(uint4*)&sQs[r * RSK + c0 + 8 * u] = pQ[u];
            *(uint4*)&sWk[r * RSK + c0 + 8 * u] = pWk[u];
            const unsigned short* kp = (const unsigned short*)&pK[u];
#pragma unroll
            for (int e = 0; e < 8; ++e) {
                const int c = c0 + 8 * u + e;
                sKT[c * RST + ((((r >> 3) ^ (c >> 3)) & 7) << 3) + (r & 7)] = kp[e];
            }
        }
        *(uint4*)&sWqk[r * RST + cw] = pWqk;

        // gates (cumulative log-decay scan, wave 0 only)
        {
            float gl = pGl;
            if (t < 64) {
#pragma unroll
                for (int off = 1; off < 64; off <<= 1) {
                    float v = __shfl_up(gl, off, 64);
                    if (lane >= off) gl += v;
                }
                float gc = __shfl(gl, 63, 64);
                sEG[t]  = __expf(gl);
                sEGd[t] = __expf(gc - gl);
            }
        }

        if (ch + 1 < NCHUNK) PF(ch + 1);   // next-chunk loads fly across compute
        __syncthreads();   // B

        // ---- Delta = U + Wkn . ST (wave w: dv = 16w + l16) ----
#pragma unroll
        for (int kk = 0; kk < 4; ++kk) {
            bfrag b0 = *(const bfrag*)&sSTb[(16 * w + l16) * RSK + 32 * kk + quad8];
#pragma unroll
            for (int mt = 0; mt < 4; ++mt) {
                bfrag af = *(const bfrag*)&sWk[(16 * mt + l16) * RSK + 32 * kk + quad8];
                accD[mt] = __builtin_amdgcn_mfma_f32_16x16x32_bf16(af, b0, accD[mt], 0, 0, 0);
            }
        }

        // ---- packed Delta^T / decayed Delta^T writes ----
        {
            const int dv = 16 * w + l16;
#pragma unroll
            for (int mt = 0; mt < 4; ++mt) {
                const int i0 = 16 * mt + quad * 4;
                const float e0 = sEGd[i0], e1 = sEGd[i0 + 1], e2 = sEGd[i0 + 2], e3 = sEGd[i0 + 3];
                const float d0 = accD[mt][0], d1 = accD[mt][1];
                const float d2 = accD[mt][2], d3 = accD[mt][3];
                *(uint32_t*)&sDT[dv * RST + i0]      = pk2(d0, d1);
                *(uint32_t*)&sDT[dv * RST + i0 + 2]  = pk2(d2, d3);
                *(uint32_t*)&sDdT[dv * RST + i0]     = pk2(d0 * e0, d1 * e1);
                *(uint32_t*)&sDdT[dv * RST + i0 + 2] = pk2(d2 * e2, d3 * e3);
            }
        }
        __syncthreads();   // D

        // ---- O = eG*(Q ST) + Wqk . Delta (wave pair: rows 16rg, dv half dh) ----
        ffrag accO[4];
#pragma unroll
        for (int nt = 0; nt < 4; ++nt) accO[nt] = (ffrag)0.f;
#pragma unroll
        for (int kk = 0; kk < 4; ++kk) {
            bfrag af = *(const bfrag*)&sQs[(16 * rg + l16) * RSK + 32 * kk + quad8];
#pragma unroll
            for (int nt = 0; nt < 4; ++nt) {
                bfrag bf = *(const bfrag*)&sSTb[(64 * dh + 16 * nt + l16) * RSK + 32 * kk + quad8];
                accO[nt] = __builtin_amdgcn_mfma_f32_16x16x32_bf16(af, bf, accO[nt], 0, 0, 0);
            }
        }
#pragma unroll
        for (int nt = 0; nt < 4; ++nt)
#pragma unroll
            for (int reg = 0; reg < 4; ++reg)
                accO[nt][reg] *= sEG[16 * rg + quad * 4 + reg];
#pragma unroll
        for (int kk = 0; kk < 2; ++kk) {
            bfrag af = *(const bfrag*)&sWqk[(16 * rg + l16) * RST + 32 * kk + quad8];
#pragma unroll
            for (int nt = 0; nt < 4; ++nt) {
                bfrag bf = *(const bfrag*)&sDT[(64 * dh + 16 * nt + l16) * RST + 32 * kk + quad8];
                accO[nt] = __builtin_amdgcn_mfma_f32_16x16x32_bf16(af, bf, accO[nt], 0, 0, 0);
            }
        }

        // RMSNorm partials for this dv-half (combine with partner wave after E)
        float p4[4];
#pragma unroll
        for (int reg = 0; reg < 4; ++reg) {
            float p = 0.f;
#pragma unroll
            for (int nt = 0; nt < 4; ++nt) p += accO[nt][reg] * accO[nt][reg];
#pragma unroll
            for (int m = 1; m < 16; m <<= 1) p += __shfl_xor(p, m, 64);
            p4[reg] = p;
        }
        if (l16 == 0) {
#pragma unroll
            for (int reg = 0; reg < 4; ++reg) sP[w * 16 + quad * 4 + reg] = p4[reg];
        }

        // ---- state update: ST = eGc*ST + DdT . KT (own dv rows; within-wave) ----
        {
            const float eGc = sEG[63];
#pragma unroll
            for (int nt = 0; nt < 8; ++nt)
#pragma unroll
                for (int reg = 0; reg < 4; ++reg) accS[nt][reg] *= eGc;
#pragma unroll
            for (int kk = 0; kk < 2; ++kk) {
                bfrag a0 = *(const bfrag*)&sDdT[(16 * w + l16) * RST + 32 * kk + quad8];
#pragma unroll
                for (int nt = 0; nt < 8; ++nt) {
                    const int ck = 16 * nt + l16;
                    bfrag bk = *(const bfrag*)&sKT[ck * RST +
                                 ((((4 * kk + quad) ^ (ck >> 3)) & 7) << 3)];
                    accS[nt] = __builtin_amdgcn_mfma_f32_16x16x32_bf16(a0, bk, accS[nt], 0, 0, 0);
                }
            }
        }
        __syncthreads();   // E: all STb/DT/DdT/KT reads done; sP written

        // ---- epilogue: combine pair partials, gated RMSNorm, write y over z ----
        {
            float inv[4];
#pragma unroll
            for (int reg = 0; reg < 4; ++reg) {
                float pp = p4[reg] + sP[(w ^ 1) * 16 + quad * 4 + reg];
                inv[reg] = rsqrtf(pp * (1.f / 128.f) + EPS);
            }
            unsigned short* zw =
                z_io + (bL + l0 + 16 * rg + quad * 4) * (size_t)VAL_DIM + h * DV + 64 * dh + l16;
#pragma unroll
            for (int nt = 0; nt < 4; ++nt) {
                const float nwv = sNW[64 * dh + 16 * nt + l16];
#pragma unroll
                for (int reg = 0; reg < 4; ++reg) {
                    float zv = bf2f(pz[nt][reg]);
                    float y = accO[nt][reg] * inv[reg] * nwv * (zv / (1.f + __expf(-zv)));
                    zw[(size_t)reg * VAL_DIM + 16 * nt] = f2bf(y);
                }
            }
        }

        // ---- materialize STb (bf16) for next chunk (own dv rows) ----
#pragma unroll
        for (int nt = 0; nt < 8; ++nt)
#pragma unroll
            for (int reg = 0; reg < 4; ++reg)
                sSTb[(16 * w + quad * 4 + reg) * RSK + 16 * nt + l16] = f2bf(accS[nt][reg]);
    }
}

// ---------------- launch ----------------
extern "C" void kernel_launch(void* const* d_in, const int* in_sizes, int n_in,
                              void* d_out, int out_size, void* d_ws, size_t ws_size,
                              hipStream_t stream)
{
    const float* x        = (const float*)d_in[0];
    const float* W_qkv    = (const float*)d_in[1];
    const float* W_z      = (const float*)d_in[2];
    const float* W_a      = (const float*)d_in[3];
    const float* W_b      = (const float*)d_in[4];
    const float* conv_w   = (const float*)d_in[5];
    const float* A_log    = (const float*)d_in[6];
    const float* dt_bias  = (const float*)d_in[7];
    const float* norm_w   = (const float*)d_in[8];
    const float* W_out    = (const float*)d_in[9];
    float* out = (float*)d_out;
    char*  ws  = (char*)d_ws;

    if (ws_size < WS_NEED_BYTES) return;

    unsigned short* qkv = (unsigned short*)(ws + OFF_QKV);
    unsigned short* z   = (unsigned short*)(ws + OFF_Z);
    float* a    = (float*)(ws + OFF_A);
    float* bbuf = (float*)(ws + OFF_B);
    float* gl   = (float*)(ws + OFF_G);
    float* beta = (float*)(ws + OFF_BETA);
    float* Ubuf = (float*)(ws + OFF_U);
    unsigned short* Wqkbuf = (unsigned short*)(ws + OFF_WQK);
    unsigned short* hbuf   = (unsigned short*)(ws + OFF_HALO);
    unsigned short* Wcat   = (unsigned short*)(ws + OFF_WCAT);  // overlay on U
    unsigned short* xb     = (unsigned short*)(ws + OFF_XB);    // overlay on Wqk
    unsigned short* Wob    = (unsigned short*)(ws + OFF_WOB);   // overlay on U

    static bool attr_set = false;
    if (!attr_set) {
        (void)hipFuncSetAttribute((const void*)chunk_prep,
                                  hipFuncAttributeMaxDynamicSharedMemorySize, P1_SMEM);
        (void)hipFuncSetAttribute((const void*)chunk_scan2,
                                  hipFuncAttributeMaxDynamicSharedMemorySize, P2_SMEM);
        (void)hipFuncSetAttribute((const void*)gemm_inproj_bf,
                                  hipFuncAttributeMaxDynamicSharedMemorySize, 131072);
        attr_set = true;
    }

    // 0. pre-convert operands to bf16 (Wcat overlays U-region, xb overlays Wqk-region)
    cvt_wcat<<<NPAD, 256, 0, stream>>>(W_qkv, W_z, W_a, W_b, Wcat);
    cvt_f32bf<<<(int)ROWS, 256, 0, stream>>>(x, xb, DIM);
    // 1. fused input projections (bf16 MFMA GEMM, 256^2 dbuf)
    gemm_inproj_bf<<<(NPAD / 256) * 16, 512, 131072, stream>>>(xb, Wcat, qkv, z, a, bbuf);
    // 2. depthwise causal conv + silu (L-tiled, halo snapshot first)
    conv_halo<<<(B * CONV_LT * CONV_DIM) / 256, 256, 0, stream>>>(qkv, hbuf);
    conv_silu<<<(B * CONV_LT * CONV_DIM) / 256, 256, 0, stream>>>(qkv, conv_w, hbuf);
    // 3. l2norm q,k heads
    normqk<<<(B * L * 2 * HK) / 4, 256, 0, stream>>>(qkv);
    // 4. gate coefficients (log-space g)
    gatecoef<<<(B * L * HV) / 256, 256, 0, stream>>>(a, bbuf, A_log, dt_bias, gl, beta);
    // 5a. parallel chunk prep: A, Wqk, solve -> U (f32, overwrites Wcat), Wkn (v-slot)
    chunk_prep<<<NCH_TOT, 256, P1_SMEM, stream>>>(qkv, gl, beta, Ubuf, Wqkbuf);
    // 5b. sequential scan (8 waves, pipelined): Delta/O/state + fused gated RMSNorm
    chunk_scan2<<<B * HV, 512, P2_SMEM, stream>>>(qkv, gl, Ubuf, Wqkbuf, z, norm_w);
    // 5c. convert W_out to bf16 (U dead now; overlay)
    cvt_f32bf<<<DIM, 256, 0, stream>>>(W_out, Wob, VAL_DIM);
    // 6. output projection (bf16 MFMA GEMM, 128^2 dbuf)
    gemm_outproj_bf<<<(ROWS / 128) * (DIM / 128), 256, 0, stream>>>(z, Wob, out);
}

// Round 7
// 924.799 us; speedup vs baseline: 1.2175x; 1.0449x over previous
//
#include <hip/hip_runtime.h>
#include <hip/hip_bf16.h>
#include <cstddef>
#include <cstdint>

// ---------------- problem constants ----------------
constexpr int B = 2, L = 2048, DIM = 2048;
constexpr int HK = 16, HV = 32, DK = 128, DV = 128;
constexpr int KEY_DIM = HK * DK;                    // 2048
constexpr int VAL_DIM = HV * DV;                    // 4096
constexpr int CONV_DIM = 2 * KEY_DIM + VAL_DIM;     // 8192
constexpr int NPROJ = CONV_DIM + VAL_DIM + HV + HV; // 12352
constexpr int NPAD  = ((NPROJ + 255) / 256) * 256;  // 12544 (128/256-tileable)
constexpr size_t ROWS = (size_t)B * L;              // 4096
constexpr float EPS = 1e-6f;
constexpr int CHUNK = 64, NCHUNK = L / CHUNK;       // 32 chunks
constexpr int NCH_TOT = B * HV * NCHUNK;            // 2048 chunk-head blocks
constexpr int CONV_LT = 8;                          // conv L-tiles
constexpr int CONV_TL = L / CONV_LT;                // 256

// workspace layout (BYTE offsets). Total ~188 MB (bf16 staging overlaid).
constexpr size_t OFF_QKV  = 0;                                   // bf16
constexpr size_t OFF_Z    = OFF_QKV + ROWS * CONV_DIM * 2;       // bf16 (y in-place)
constexpr size_t OFF_A    = OFF_Z   + ROWS * VAL_DIM * 2;        // f32
constexpr size_t OFF_B    = OFF_A   + ROWS * HV * 4;
constexpr size_t OFF_G    = OFF_B   + ROWS * HV * 4;             // g (log-space)
constexpr size_t OFF_BETA = OFF_G   + ROWS * HV * 4;
constexpr size_t OFF_U    = OFF_BETA + ROWS * HV * 4;            // f32 U = T(BV)
constexpr size_t OFF_WQK  = OFF_U + (size_t)NCH_TOT * CHUNK * DV * 4;  // bf16 Wqk
constexpr size_t OFF_HALO = OFF_WQK + (size_t)NCH_TOT * CHUNK * CHUNK * 2; // conv halos
constexpr size_t WS_NEED_BYTES = OFF_HALO + (size_t)3 * B * CONV_LT * CONV_DIM * 2;
// overlays (lifetime-disjoint):
constexpr size_t OFF_WCAT = OFF_U;    // Wcat bf16 (NPAD x DIM) until inproj done
constexpr size_t OFF_XB   = OFF_WQK;  // x bf16 until inproj done
constexpr size_t OFF_WOB  = OFF_U;    // Wout bf16 after chunk_scan2
static_assert((size_t)NPAD * DIM * 2 <= (size_t)NCH_TOT * CHUNK * DV * 4, "Wcat fits U");

// ---------------- bf16 helpers ----------------
__device__ __forceinline__ float bf2f(unsigned short u) {
    union { float f; uint32_t i; } c; c.i = ((uint32_t)u) << 16; return c.f;
}
__device__ __forceinline__ unsigned short f2bf(float f) {
    union { float f; uint32_t u; } c; c.f = f;
    uint32_t u = c.u + 0x7FFFu + ((c.u >> 16) & 1u);   // RTNE
    return (unsigned short)(u >> 16);
}
__device__ __forceinline__ uint32_t pk2(float a, float b) {
    return (uint32_t)f2bf(a) | ((uint32_t)f2bf(b) << 16);
}

// MFMA fragment types (16x16x32 bf16)
typedef __attribute__((ext_vector_type(8))) short bfrag;   // 8 bf16
typedef __attribute__((ext_vector_type(4))) float ffrag;   // 4 f32

// async global->LDS, 16B per lane (dest is wave-uniform base + lane*16)
__device__ __forceinline__ void gload16(const unsigned short* g, unsigned short* l) {
    __builtin_amdgcn_global_load_lds(
        (const __attribute__((address_space(1))) uint32_t*)g,
        (__attribute__((address_space(3))) uint32_t*)l, 16, 0, 0);
}

// ================= f32 -> bf16 conversion kernels =================
__device__ __forceinline__ const float* w_row_multi(int n, const float* Wq, const float* Wz,
                                                    const float* Wa, const float* Wb) {
    if (n < CONV_DIM)                return Wq + (size_t)n * DIM;
    if (n < CONV_DIM + VAL_DIM)      return Wz + (size_t)(n - CONV_DIM) * DIM;
    if (n < CONV_DIM + VAL_DIM + HV) return Wa + (size_t)(n - CONV_DIM - VAL_DIM) * DIM;
    return Wb + (size_t)(n - CONV_DIM - VAL_DIM - HV) * DIM;
}

__global__ __launch_bounds__(256) void cvt_wcat(
    const float* __restrict__ Wq, const float* __restrict__ Wz,
    const float* __restrict__ Wa, const float* __restrict__ Wb,
    unsigned short* __restrict__ dst)
{
    const int r = blockIdx.x;            // 0..NPAD-1
    const int c = threadIdx.x * 8;       // 256*8 = 2048 = DIM
    uint4 o;
    if (r < NPROJ) {
        const float* s = w_row_multi(r, Wq, Wz, Wa, Wb) + c;
        float4 v0 = *(const float4*)s;
        float4 v1 = *(const float4*)(s + 4);
        o = make_uint4(pk2(v0.x, v0.y), pk2(v0.z, v0.w), pk2(v1.x, v1.y), pk2(v1.z, v1.w));
    } else {
        o = make_uint4(0u, 0u, 0u, 0u);
    }
    *(uint4*)&dst[(size_t)r * DIM + c] = o;
}

__global__ __launch_bounds__(256) void cvt_f32bf(const float* __restrict__ src,
                                                 unsigned short* __restrict__ dst, int cols)
{
    const size_t r = blockIdx.x;
    for (int c = threadIdx.x * 8; c < cols; c += 256 * 8) {
        const float* s = src + r * cols + c;
        float4 v0 = *(const float4*)s;
        float4 v1 = *(const float4*)(s + 4);
        *(uint4*)&dst[r * cols + c] =
            make_uint4(pk2(v0.x, v0.y), pk2(v0.z, v0.w), pk2(v1.x, v1.y), pk2(v1.z, v1.w));
    }
}

// ================= shared GEMM epilogue helper (inproj) =================
__device__ __forceinline__ void store_multi(int m, int n, float v,
                                            unsigned short* qkv, unsigned short* z,
                                            float* a, float* b) {
    if (n < CONV_DIM) {
        qkv[(size_t)m * CONV_DIM + n] = f2bf(v);
    } else if (n < CONV_DIM + VAL_DIM) {
        z[(size_t)m * VAL_DIM + (n - CONV_DIM)] = f2bf(v);
    } else if (n < CONV_DIM + VAL_DIM + HV) {
        a[(size_t)m * HV + (n - CONV_DIM - VAL_DIM)] = v;
    } else if (n < NPROJ) {
        b[(size_t)m * HV + (n - CONV_DIM - VAL_DIM - HV)] = v;
    }
}

constexpr int BK = 64;

// ===================================================================
// 256x128-tile GEMM with 3-deep LDS pipeline + counted vmcnt (T4).
// 512 threads / 8 waves (4M x 2N), per-wave 64x64 out, 32 MFMA/K-tile.
// LDS: 3 bufs x (A 256x64 + B 128x64) bf16 = 144 KiB.
// Per K-tile: STAGE(kt+2) -> vmcnt(12) -> s_barrier -> MFMA -> s_barrier.
// vmcnt never drains to 0 in steady state (loads span 2 K-tiles).
// Race audit: WAR - S(kt+2) writes buf[(kt-1)%3], all reads of it (C(kt-1))
// completed before the trailing barrier of iter kt-1; RAW - barrier follows
// each wave's own vmcnt(12) => all waves' tile-kt loads landed before C(kt).
// ===================================================================
constexpr int GBUF = 24576;                 // ushorts per buffer (48 KiB)
constexpr int GEMM_SMEM = 3 * GBUF * 2;     // 147456 B

__global__ __launch_bounds__(512, 1) void gemm_inproj_bf(
    const unsigned short* __restrict__ xb,     // (ROWS, DIM)
    const unsigned short* __restrict__ Wcat,   // (NPAD, DIM), pad rows zero
    unsigned short* __restrict__ qkv, unsigned short* __restrict__ z,
    float* __restrict__ a_out, float* __restrict__ b_out)
{
    extern __shared__ __align__(16) unsigned short lds[];

    constexpr int NT  = DIM / BK;              // 32 K-tiles
    constexpr int NBY = (int)ROWS / 256;       // 16
    constexpr int NBX = NPAD / 128;            // 98
    constexpr int NB  = NBY * NBX;             // 1568 (div by 8)
    const int id  = blockIdx.x;
    const int swz = (id & 7) * (NB >> 3) + (id >> 3);
    const int by  = swz & 15;                  // row tile
    const int bx  = swz >> 4;                  // col panel (L2 locality)
    const int row0 = by * 256;
    const int col0 = bx * 128;

    const int t = threadIdx.x, lane = t & 63, wid = t >> 6;
    const int wr = wid >> 1, wc = wid & 1;
    const int quad = lane >> 4, l16 = lane & 15;
    const int x7 = l16 & 7;

    ffrag acc[4][4];
#pragma unroll
    for (int i = 0; i < 4; ++i)
#pragma unroll
        for (int j = 0; j < 4; ++j) acc[i][j] = (ffrag)0.f;

    const int srow = t >> 3;                   // 0..63
    const int scol = (((t & 7) ^ (srow & 7)) * 8);   // pre-swizzled source slot
    const unsigned short* aS = xb   + (size_t)(row0 + srow) * DIM + scol;
    const unsigned short* bS = Wcat + (size_t)(col0 + srow) * DIM + scol;
    unsigned short* aD0 = lds + (wid * 8) * 64;           // wave-uniform dest
    unsigned short* bD0 = lds + 16384 + (wid * 8) * 64;

    auto STAGE = [&](int kt) {
        const int b = kt % 3;
        unsigned short* aD = aD0 + b * GBUF;
        unsigned short* bD = bD0 + b * GBUF;
        const int k0 = kt * BK;
#pragma unroll
        for (int g = 0; g < 4; ++g)
            gload16(aS + (size_t)(g * 64) * DIM + k0, aD + g * 64 * 64);
#pragma unroll
        for (int g = 0; g < 2; ++g)
            gload16(bS + (size_t)(g * 64) * DIM + k0, bD + g * 64 * 64);
    };

    auto COMPUTE = [&](int kt) {
        const int b = kt % 3;
        const unsigned short* A  = lds + b * GBUF;
        const unsigned short* Bm = lds + b * GBUF + 16384;
#pragma unroll
        for (int kk = 0; kk < 2; ++kk) {
            const int so = ((kk * 4 + quad) ^ x7) * 8;
            bfrag aF[4], bF[4];
#pragma unroll
            for (int m = 0; m < 4; ++m)
                aF[m] = *(const bfrag*)&A[(wr * 64 + m * 16 + l16) * 64 + so];
#pragma unroll
            for (int n = 0; n < 4; ++n)
                bF[n] = *(const bfrag*)&Bm[(wc * 64 + n * 16 + l16) * 64 + so];
#pragma unroll
            for (int m = 0; m < 4; ++m)
#pragma unroll
                for (int n = 0; n < 4; ++n)
                    acc[m][n] = __builtin_amdgcn_mfma_f32_16x16x32_bf16(
                        aF[m], bF[n], acc[m][n], 0, 0, 0);
        }
    };

    STAGE(0); STAGE(1);
    asm volatile("s_waitcnt vmcnt(6)" ::: "memory");   // tile 0 landed (own)
    asm volatile("s_barrier" ::: "memory");            // initial trailing barrier
    for (int kt = 0; kt < NT; ++kt) {
        if (kt + 2 < NT) {
            STAGE(kt + 2);
            asm volatile("s_waitcnt vmcnt(12)" ::: "memory");  // tile kt landed
        } else if (kt + 1 < NT) {
            asm volatile("s_waitcnt vmcnt(6)" ::: "memory");
        } else {
            asm volatile("s_waitcnt vmcnt(0)" ::: "memory");
        }
        asm volatile("s_barrier" ::: "memory");        // all waves: tile kt ready
        COMPUTE(kt);
        asm volatile("s_barrier" ::: "memory");        // reads of buf kt done
    }

#pragma unroll
    for (int m = 0; m < 4; ++m)
#pragma unroll
        for (int n = 0; n < 4; ++n) {
            int gr = row0 + wr * 64 + m * 16 + quad * 4;
            int gc = col0 + wc * 64 + n * 16 + l16;
#pragma unroll
            for (int reg = 0; reg < 4; ++reg)
                store_multi(gr + reg, gc, acc[m][n][reg], qkv, z, a_out, b_out);
        }
}

__global__ __launch_bounds__(512, 1) void gemm_outproj_bf(
    const unsigned short* __restrict__ A,    // (ROWS, VAL_DIM)
    const unsigned short* __restrict__ Wb,   // (DIM, VAL_DIM)
    float* __restrict__ C)                   // (ROWS, DIM)
{
    extern __shared__ __align__(16) unsigned short lds[];

    constexpr int NT  = VAL_DIM / BK;          // 64 K-tiles
    constexpr int NBY = (int)ROWS / 256;       // 16
    constexpr int NBX = DIM / 128;             // 16
    constexpr int NB  = NBY * NBX;             // 256 = exactly one CU round
    const int id  = blockIdx.x;
    const int swz = (id & 7) * (NB >> 3) + (id >> 3);
    const int by  = swz & 15;
    const int bx  = swz >> 4;
    const int row0 = by * 256;
    const int col0 = bx * 128;

    const int t = threadIdx.x, lane = t & 63, wid = t >> 6;
    const int wr = wid >> 1, wc = wid & 1;
    const int quad = lane >> 4, l16 = lane & 15;
    const int x7 = l16 & 7;

    ffrag acc[4][4];
#pragma unroll
    for (int i = 0; i < 4; ++i)
#pragma unroll
        for (int j = 0; j < 4; ++j) acc[i][j] = (ffrag)0.f;

    const int srow = t >> 3;
    const int scol = (((t & 7) ^ (srow & 7)) * 8);
    const unsigned short* aS = A  + (size_t)(row0 + srow) * VAL_DIM + scol;
    const unsigned short* bS = Wb + (size_t)(col0 + srow) * VAL_DIM + scol;
    unsigned short* aD0 = lds + (wid * 8) * 64;
    unsigned short* bD0 = lds + 16384 + (wid * 8) * 64;

    auto STAGE = [&](int kt) {
        const int b = kt % 3;
        unsigned short* aD = aD0 + b * GBUF;
        unsigned short* bD = bD0 + b * GBUF;
        const int k0 = kt * BK;
#pragma unroll
        for (int g = 0; g < 4; ++g)
            gload16(aS + (size_t)(g * 64) * VAL_DIM + k0, aD + g * 64 * 64);
#pragma unroll
        for (int g = 0; g < 2; ++g)
            gload16(bS + (size_t)(g * 64) * VAL_DIM + k0, bD + g * 64 * 64);
    };

    auto COMPUTE = [&](int kt) {
        const int b = kt % 3;
        const unsigned short* Am = lds + b * GBUF;
        const unsigned short* Bm = lds + b * GBUF + 16384;
#pragma unroll
        for (int kk = 0; kk < 2; ++kk) {
            const int so = ((kk * 4 + quad) ^ x7) * 8;
            bfrag aF[4], bF[4];
#pragma unroll
            for (int m = 0; m < 4; ++m)
                aF[m] = *(const bfrag*)&Am[(wr * 64 + m * 16 + l16) * 64 + so];
#pragma unroll
            for (int n = 0; n < 4; ++n)
                bF[n] = *(const bfrag*)&Bm[(wc * 64 + n * 16 + l16) * 64 + so];
#pragma unroll
            for (int m = 0; m < 4; ++m)
#pragma unroll
                for (int n = 0; n < 4; ++n)
                    acc[m][n] = __builtin_amdgcn_mfma_f32_16x16x32_bf16(
                        aF[m], bF[n], acc[m][n], 0, 0, 0);
        }
    };

    STAGE(0); STAGE(1);
    asm volatile("s_waitcnt vmcnt(6)" ::: "memory");
    asm volatile("s_barrier" ::: "memory");
    for (int kt = 0; kt < NT; ++kt) {
        if (kt + 2 < NT) {
            STAGE(kt + 2);
            asm volatile("s_waitcnt vmcnt(12)" ::: "memory");
        } else if (kt + 1 < NT) {
            asm volatile("s_waitcnt vmcnt(6)" ::: "memory");
        } else {
            asm volatile("s_waitcnt vmcnt(0)" ::: "memory");
        }
        asm volatile("s_barrier" ::: "memory");
        COMPUTE(kt);
        asm volatile("s_barrier" ::: "memory");
    }

#pragma unroll
    for (int m = 0; m < 4; ++m)
#pragma unroll
        for (int n = 0; n < 4; ++n) {
            int gr = row0 + wr * 64 + m * 16 + quad * 4;
            int gc = col0 + wc * 64 + n * 16 + l16;
#pragma unroll
            for (int reg = 0; reg < 4; ++reg)
                C[(size_t)(gr + reg) * DIM + gc] = acc[m][n][reg];
        }
}

// ================= conv halo snapshot (race-free tiling) =================
__global__ __launch_bounds__(256) void conv_halo(const unsigned short* __restrict__ qkv,
                                                 unsigned short* __restrict__ hbuf)
{
    int idx = blockIdx.x * 256 + threadIdx.x;     // B * CONV_LT * CONV_DIM
    int c    = idx & (CONV_DIM - 1);
    int tile = (idx >> 13) & (CONV_LT - 1);
    int b    = idx >> 16;
    int l0 = tile * CONV_TL;
    const unsigned short* p = qkv + (size_t)b * L * CONV_DIM + c;
#pragma unroll
    for (int j = 0; j < 3; ++j) {
        unsigned short v = (tile > 0) ? p[(size_t)(l0 - 3 + j) * CONV_DIM] : (unsigned short)0;
        hbuf[((size_t)j * B * CONV_LT + b * CONV_LT + tile) * CONV_DIM + c] = v;
    }
}

// ================= depthwise causal conv1d + SiLU (L-tiled) =================
__global__ __launch_bounds__(256) void conv_silu(unsigned short* __restrict__ qkv,
                                                 const float* __restrict__ conv_w,
                                                 const unsigned short* __restrict__ hbuf)
{
    int idx = blockIdx.x * 256 + threadIdx.x;     // B * CONV_LT * CONV_DIM
    int c    = idx & (CONV_DIM - 1);
    int tile = (idx >> 13) & (CONV_LT - 1);
    int b    = idx >> 16;
    const float w0 = conv_w[c * 4 + 0];
    const float w1 = conv_w[c * 4 + 1];
    const float w2 = conv_w[c * 4 + 2];
    const float w3 = conv_w[c * 4 + 3];
    unsigned short* p = qkv + ((size_t)b * L + tile * CONV_TL) * CONV_DIM + c;
    const size_t hb = (size_t)b * CONV_LT + tile;
    float x0 = bf2f(hbuf[((size_t)0 * B * CONV_LT + hb) * CONV_DIM + c]);
    float x1 = bf2f(hbuf[((size_t)1 * B * CONV_LT + hb) * CONV_DIM + c]);
    float x2 = bf2f(hbuf[((size_t)2 * B * CONV_LT + hb) * CONV_DIM + c]);
    for (int l0 = 0; l0 < CONV_TL; l0 += 8) {
        float xv[8];
#pragma unroll
        for (int j = 0; j < 8; ++j) xv[j] = bf2f(p[(size_t)(l0 + j) * CONV_DIM]);
#pragma unroll
        for (int j = 0; j < 8; ++j) {
            float h = w0 * x0 + w1 * x1 + w2 * x2 + w3 * xv[j];
            float s = h / (1.f + __expf(-h));
            p[(size_t)(l0 + j) * CONV_DIM] = f2bf(s);
            x0 = x1; x1 = x2; x2 = xv[j];
        }
    }
}

// ================= l2norm of q,k heads =================
__global__ __launch_bounds__(256) void normqk(unsigned short* __restrict__ qkv)
{
    int wid  = blockIdx.x * 4 + (threadIdx.x >> 6);
    int lane = threadIdx.x & 63;
    int hk  = wid & 15;
    int sel = (wid >> 4) & 1;
    int row = wid >> 5;
    unsigned short* p = qkv + (size_t)row * CONV_DIM + sel * KEY_DIM + hk * DK;
    float x0 = bf2f(p[lane]), x1 = bf2f(p[lane + 64]);
    float ss = x0 * x0 + x1 * x1;
#pragma unroll
    for (int o = 32; o >= 1; o >>= 1) ss += __shfl_xor(ss, o);
    float sc = rsqrtf(ss + 1e-6f);
    if (sel == 0) sc *= 0.08838834764831845f;   // DK^-0.5
    p[lane]      = f2bf(x0 * sc);
    p[lane + 64] = f2bf(x1 * sc);
}

// ================= gate coefficients: g (log) and beta =================
__global__ __launch_bounds__(256) void gatecoef(const float* __restrict__ a_buf,
                                                const float* __restrict__ b_buf,
                                                const float* __restrict__ A_log,
                                                const float* __restrict__ dt_bias,
                                                float* __restrict__ glog,
                                                float* __restrict__ beta)
{
    int idx = blockIdx.x * blockDim.x + threadIdx.x;
    int h = idx & (HV - 1);
    float av = a_buf[idx];
    float bv = b_buf[idx];
    float x  = av + dt_bias[h];
    float sp = (x > 20.f) ? x : log1pf(__expf(x));
    glog[idx] = -__expf(A_log[h]) * sp;
    beta[idx] = 1.f / (1.f + __expf(-bv));
}

// ===================================================================
// Two-pass chunked gated delta rule (unchanged from round 6).
// ===================================================================

// shared strides
constexpr int RSK  = 136;   // 128-wide bf16 rows (128 data + 8 pad)
constexpr int RST  = 72;    // 64-wide bf16 rows (64 data + 8 pad)
constexpr int RSTD = 68;    // pass-1 X^T rows (64 data + 4 pad)
constexpr int RSR1 = 260;   // pass-1 RHS f32 rows (256 data + 4 pad)

// ---- pass-1 LDS layout ----
constexpr int P1_oKs  = 0;                       // 64*136*2 = 17408
constexpr int P1_oQs  = P1_oKs + 64 * RSK * 2;   // 17408
constexpr int P1_oDT  = 0;                       // overlay Ks+Qs: 256*68*2 = 34816
constexpr int P1_oAf  = P1_oQs + 64 * RSK * 2;   // 34816 (64*72*2 = 9216)
constexpr int P1_oRHS = P1_oAf + 64 * RST * 2;   // 44032 (64*260*4 = 66560)
constexpr int P1_oG   = P1_oRHS + 64 * RSR1 * 4; // 110592
constexpr int P1_oEG  = P1_oG + 256;
constexpr int P1_oBs  = P1_oEG + 256;
constexpr int P1_SMEM = P1_oBs + 256;            // 111616

__global__ __launch_bounds__(256, 1) void chunk_prep(
    unsigned short* __restrict__ qkv,     // v-slot overwritten with Wkn
    const float* __restrict__ glog,
    const float* __restrict__ beta,
    float* __restrict__ Ubuf,
    unsigned short* __restrict__ Wqkbuf)
{
    extern __shared__ __align__(16) char smem[];
    unsigned short* sKs = (unsigned short*)(smem + P1_oKs);
    unsigned short* sQs = (unsigned short*)(smem + P1_oQs);
    unsigned short* sDT = (unsigned short*)(smem + P1_oDT);
    unsigned short* sAf = (unsigned short*)(smem + P1_oAf);
    float* sRHS = (float*)(smem + P1_oRHS);
    float* sG   = (float*)(smem + P1_oG);
    float* sEG  = (float*)(smem + P1_oEG);
    float* sBs  = (float*)(smem + P1_oBs);

    const int bid = blockIdx.x;
    const int ch = bid & (NCHUNK - 1);
    const int h  = (bid >> 5) & (HV - 1);
    const int bb = bid >> 10;
    const int hk = h >> 1;
    const int t    = threadIdx.x;
    const int w    = t >> 6;
    const int lane = t & 63;
    const int quad = lane >> 4;
    const int l16  = lane & 15;
    const int quad8 = quad * 8;
    const size_t bL = (size_t)bb * L;
    const int l0 = ch * CHUNK;
    const int VOFF = 2 * KEY_DIM + h * DV;

    // ---- loads ----
    {
        const int r  = t >> 2;
        const int c0 = (t & 3) * 32;
        const unsigned short* grow = qkv + (bL + l0 + r) * CONV_DIM;
        const unsigned short* gq = grow + hk * DK + c0;
        const unsigned short* gk = grow + KEY_DIM + hk * DK + c0;
#pragma unroll
        for (int u = 0; u < 4; ++u) {
            *(uint4*)&sKs[r * RSK + c0 + 8 * u] = *(const uint4*)(gk + 8 * u);
            *(uint4*)&sQs[r * RSK + c0 + 8 * u] = *(const uint4*)(gq + 8 * u);
        }
        if (t < 64) {
            float gl = glog[(bL + l0 + t) * HV + h];
#pragma unroll
            for (int off = 1; off < 64; off <<= 1) {
                float v = __shfl_up(gl, off, 64);
                if (lane >= off) gl += v;
            }
            sG[t]  = gl;
            sEG[t] = __expf(gl);
            sBs[t] = beta[(bL + l0 + t) * HV + h];
        }
    }
    __syncthreads();

    // ---- A = K K^T, Wqk = Q K^T (wave w: cols j in [16w,16w+16)) ----
    {
        ffrag accA[4], accW[4];
#pragma unroll
        for (int mt = 0; mt < 4; ++mt) { accA[mt] = (ffrag)0.f; accW[mt] = (ffrag)0.f; }
#pragma unroll
        for (int kk = 0; kk < 4; ++kk) {
            bfrag bf = *(const bfrag*)&sKs[(16 * w + l16) * RSK + 32 * kk + quad8];
#pragma unroll
            for (int mt = 0; mt < 4; ++mt) {
                bfrag ak = *(const bfrag*)&sKs[(16 * mt + l16) * RSK + 32 * kk + quad8];
                bfrag aq = *(const bfrag*)&sQs[(16 * mt + l16) * RSK + 32 * kk + quad8];
                accA[mt] = __builtin_amdgcn_mfma_f32_16x16x32_bf16(ak, bf, accA[mt], 0, 0, 0);
                accW[mt] = __builtin_amdgcn_mfma_f32_16x16x32_bf16(aq, bf, accW[mt], 0, 0, 0);
            }
        }
        const int j = 16 * w + l16;
        const float gj = sG[j];
        unsigned short* Wqp = Wqkbuf + (size_t)bid * (CHUNK * CHUNK);
#pragma unroll
        for (int mt = 0; mt < 4; ++mt)
#pragma unroll
            for (int reg = 0; reg < 4; ++reg) {
                int i = 16 * mt + quad * 4 + reg;
                float sc = __expf(sG[i] - gj);
                sAf[i * RST + j] = f2bf((j < i) ? sBs[i] * sc * accA[mt][reg] : 0.f);
                Wqp[i * CHUNK + j] = f2bf((j <= i) ? sc * accW[mt][reg] : 0.f);
            }
    }

    // ---- RHS = [ B*V | B*eG*K ] (f32) ----
    {
        const int r  = t >> 2;
        const int c0 = (t & 3) * 32;
        const float be  = sBs[r];
        const float beg = be * sEG[r];
        const unsigned short* gv = qkv + (bL + l0 + r) * CONV_DIM + VOFF + c0;
#pragma unroll
        for (int u = 0; u < 4; ++u) {
            uint4 vv = *(const uint4*)(gv + 8 * u);
            const unsigned short* vp = (const unsigned short*)&vv;
#pragma unroll
            for (int e = 0; e < 8; ++e)
                sRHS[r * RSR1 + c0 + 8 * u + e] = be * bf2f(vp[e]);
        }
#pragma unroll
        for (int u = 0; u < 4; ++u)
#pragma unroll
            for (int e = 0; e < 8; ++e)
                sRHS[r * RSR1 + 128 + c0 + 8 * u + e] =
                    beg * bf2f(sKs[r * RSK + c0 + 8 * u + e]);
    }
    __syncthreads();   // Ks/Qs reads done -> DT overlay writable

    // zero X^T staging (padding rows read by block-solve MFMAs)
    for (int u = t; u < 256 * RSTD / 2; u += 256) ((uint32_t*)sDT)[u] = 0;

    // ---- blocked forward substitution, 256 columns ----
    float* Up = Ubuf + (size_t)bid * (CHUNK * DV);
    for (int sb = 0; sb < 4; ++sb) {
        const int sb16 = 16 * sb;
        if (sb > 0) {
            const int kbn = (sb + 1) >> 1;
            ffrag c16[4];
#pragma unroll
            for (int nt = 0; nt < 4; ++nt) c16[nt] = (ffrag)0.f;
            for (int kb = 0; kb < kbn; ++kb) {
                bfrag af = *(const bfrag*)&sAf[(sb16 + l16) * RST + 32 * kb + quad8];
#pragma unroll
                for (int nt = 0; nt < 4; ++nt) {
                    bfrag bf = *(const bfrag*)&sDT[(64 * w + 16 * nt + l16) * RSTD + 32 * kb + quad8];
                    c16[nt] = __builtin_amdgcn_mfma_f32_16x16x32_bf16(af, bf, c16[nt], 0, 0, 0);
                }
            }
#pragma unroll
            for (int nt = 0; nt < 4; ++nt)
#pragma unroll
                for (int reg = 0; reg < 4; ++reg)
                    sRHS[(sb16 + quad * 4 + reg) * RSR1 + 64 * w + 16 * nt + l16] -= c16[nt][reg];
        }
        __syncthreads();
        {   // serial 16x16 unit-lower solve; thread t owns column t
            const int c = t;
            float d16[16];
#pragma unroll
            for (int e = 0; e < 16; ++e) {
                const int i = sb16 + e;
                float acc = sRHS[i * RSR1 + c];
#pragma unroll
                for (int f = 0; f < 16; ++f)
                    if (f < e) acc -= bf2f(sAf[i * RST + sb16 + f]) * d16[f];
                d16[e] = acc;
            }
#pragma unroll
            for (int e = 0; e < 16; e += 2)
                *(uint32_t*)&sDT[c * RSTD + sb16 + e] = pk2(d16[e], d16[e + 1]);
            if (c < 128) {
                float* up = Up + c;
#pragma unroll
                for (int e = 0; e < 16; ++e) up[(size_t)(sb16 + e) * DV] = d16[e];
            } else {
                unsigned short* wp = qkv + (bL + l0 + sb16) * CONV_DIM + VOFF + (c - 128);
#pragma unroll
                for (int e = 0; e < 16; ++e) wp[(size_t)e * CONV_DIM] = f2bf(-d16[e]);
            }
        }
        __syncthreads();
    }
}

// ---- pass-2 LDS layout (8-wave version) ----
constexpr int P2_oSTb = 0;                         // 128*136*2 = 34816
constexpr int P2_oWk  = P2_oSTb + 128 * RSK * 2;   // +17408
constexpr int P2_oQs  = P2_oWk + 64 * RSK * 2;     // +17408
constexpr int P2_oKT  = P2_oQs + 64 * RSK * 2;     // +18432
constexpr int P2_oWqk = P2_oKT + 128 * RST * 2;    // +9216
constexpr int P2_oDT  = P2_oWqk + 64 * RST * 2;    // +18432
constexpr int P2_oDdT = P2_oDT + 128 * RST * 2;    // +18432
constexpr int P2_oEG  = P2_oDdT + 128 * RST * 2;   // 134144
constexpr int P2_oEGd = P2_oEG + 256;              // 134400
constexpr int P2_oNW  = P2_oEGd + 256;             // 134656
constexpr int P2_oP   = P2_oNW + 512;              // 135168 (wave-pair RMS partials)
constexpr int P2_SMEM = P2_oP + 512;               // 135680

// 512 threads / 8 waves: 2 waves/SIMD for latency hiding; per-wave MFMA halves.
__global__ __launch_bounds__(512, 1) void chunk_scan2(
    const unsigned short* __restrict__ qkv,   // q,k raw; v-slot holds Wkn
    const float* __restrict__ glog,
    const float* __restrict__ Ubuf,
    const unsigned short* __restrict__ Wqkbuf,
    unsigned short* __restrict__ z_io,
    const float* __restrict__ norm_w)
{
    extern __shared__ __align__(16) char smem[];
    unsigned short* sSTb = (unsigned short*)(smem + P2_oSTb);
    unsigned short* sWk  = (unsigned short*)(smem + P2_oWk);
    unsigned short* sQs  = (unsigned short*)(smem + P2_oQs);
    unsigned short* sKT  = (unsigned short*)(smem + P2_oKT);
    unsigned short* sWqk = (unsigned short*)(smem + P2_oWqk);
    unsigned short* sDT  = (unsigned short*)(smem + P2_oDT);
    unsigned short* sDdT = (unsigned short*)(smem + P2_oDdT);
    float* sEG  = (float*)(smem + P2_oEG);
    float* sEGd = (float*)(smem + P2_oEGd);
    float* sNW  = (float*)(smem + P2_oNW);
    float* sP   = (float*)(smem + P2_oP);

    const int bb = blockIdx.x >> 5;
    const int h  = blockIdx.x & (HV - 1);
    const int hk = h >> 1;
    const int t    = threadIdx.x;            // 0..511
    const int w    = t >> 6;                 // 0..7
    const int lane = t & 63;
    const int quad = lane >> 4;
    const int l16  = lane & 15;
    const int quad8 = quad * 8;
    const int rg = w >> 1;                   // O-phase row group
    const int dh = w & 1;                    // O-phase dv half
    const size_t bL = (size_t)bb * L;
    const int VOFF = 2 * KEY_DIM + h * DV;
    const size_t chbase0 = ((size_t)bb * HV + h) * NCHUNK;

    const int r  = t >> 3;        // staging row 0..63
    const int c0 = (t & 7) * 16;  // staging col
    const int cw = (t & 7) * 8;   // Wqk col

    // persistent state: ST[dv][dk], wave w owns dv in [16w,16w+16)
    ffrag accS[8];
#pragma unroll
    for (int nt = 0; nt < 8; ++nt) accS[nt] = (ffrag)0.f;

    for (int u = t; u < 64 * RSK; u += 512) ((uint32_t*)sSTb)[u] = 0;  // 128*136 bf16
    if (t < 128) sNW[t] = norm_w[t];

    // prefetch registers (issue-early / write-late)
    uint4 pQ[2], pK[2], pWk[2], pWqk;
    float pGl;

    auto PF = [&](int ch) {
        const int l0p = ch * CHUNK;
        const unsigned short* grow = qkv + (bL + l0p + r) * CONV_DIM;
        const unsigned short* gq = grow + hk * DK + c0;
        const unsigned short* gk = grow + KEY_DIM + hk * DK + c0;
        const unsigned short* gw = grow + VOFF + c0;
#pragma unroll
        for (int u = 0; u < 2; ++u) {
            pQ[u]  = *(const uint4*)(gq + 8 * u);
            pK[u]  = *(const uint4*)(gk + 8 * u);
            pWk[u] = *(const uint4*)(gw + 8 * u);
        }
        pWqk = *(const uint4*)(Wqkbuf + (chbase0 + ch) * (CHUNK * CHUNK) + r * CHUNK + cw);
        pGl = glog[(bL + l0p + (t & 63)) * HV + h];
    };

    PF(0);

    for (int ch = 0; ch < NCHUNK; ++ch) {
        const int l0 = ch * CHUNK;
        const size_t cb = chbase0 + ch;
        __syncthreads();   // A: prev STb written; all prev-phase LDS reads done

        // ---- U -> accD direct from global ----
        ffrag accD[4];
        {
            const float* up = Ubuf + cb * (CHUNK * DV) + (size_t)(quad * 4) * DV + 16 * w + l16;
#pragma unroll
            for (int mt = 0; mt < 4; ++mt)
#pragma unroll
                for (int reg = 0; reg < 4; ++reg)
                    accD[mt][reg] = up[(size_t)(16 * mt + reg) * DV];
        }
        // ---- z gate prefetch (consumed in epilogue; wave-pair layout) ----
        unsigned short pz[4][4];
        {
            const unsigned short* zp =
                z_io + (bL + l0 + 16 * rg + quad * 4) * (size_t)VAL_DIM + h * DV + 64 * dh + l16;
#pragma unroll
            for (int nt = 0; nt < 4; ++nt)
#pragma unroll
                for (int reg = 0; reg < 4; ++reg)
                    pz[nt][reg] = zp[(size_t)reg * VAL_DIM + 16 * nt];
        }

        // ---- stage LDS from prefetch regs ----
#pragma unroll
        for (int u = 0; u < 2; ++u) {
            *(uint4*)&sQs[r * RSK + c0 + 8 * u] = pQ[u];
            *(uint4*)&sWk[r * RSK + c0 + 8 * u] = pWk[u];
            const unsigned short* kp = (const unsigned short*)&pK[u];
#pragma unroll
            for (int e = 0; e < 8; ++e) {
                const int c = c0 + 8 * u + e;
                sKT[c * RST + ((((r >> 3) ^ (c >> 3)) & 7) << 3) + (r & 7)] = kp[e];
            }
        }
        *(uint4*)&sWqk[r * RST + cw] = pWqk;

        // gates (cumulative log-decay scan, wave 0 only)
        {
            float gl = pGl;
            if (t < 64) {
#pragma unroll
                for (int off = 1; off < 64; off <<= 1) {
                    float v = __shfl_up(gl, off, 64);
                    if (lane >= off) gl += v;
                }
                float gc = __shfl(gl, 63, 64);
                sEG[t]  = __expf(gl);
                sEGd[t] = __expf(gc - gl);
            }
        }

        if (ch + 1 < NCHUNK) PF(ch + 1);   // next-chunk loads fly across compute
        __syncthreads();   // B

        // ---- Delta = U + Wkn . ST (wave w: dv = 16w + l16) ----
#pragma unroll
        for (int kk = 0; kk < 4; ++kk) {
            bfrag b0 = *(const bfrag*)&sSTb[(16 * w + l16) * RSK + 32 * kk + quad8];
#pragma unroll
            for (int mt = 0; mt < 4; ++mt) {
                bfrag af = *(const bfrag*)&sWk[(16 * mt + l16) * RSK + 32 * kk + quad8];
                accD[mt] = __builtin_amdgcn_mfma_f32_16x16x32_bf16(af, b0, accD[mt], 0, 0, 0);
            }
        }

        // ---- packed Delta^T / decayed Delta^T writes ----
        {
            const int dv = 16 * w + l16;
#pragma unroll
            for (int mt = 0; mt < 4; ++mt) {
                const int i0 = 16 * mt + quad * 4;
                const float e0 = sEGd[i0], e1 = sEGd[i0 + 1], e2 = sEGd[i0 + 2], e3 = sEGd[i0 + 3];
                const float d0 = accD[mt][0], d1 = accD[mt][1];
                const float d2 = accD[mt][2], d3 = accD[mt][3];
                *(uint32_t*)&sDT[dv * RST + i0]      = pk2(d0, d1);
                *(uint32_t*)&sDT[dv * RST + i0 + 2]  = pk2(d2, d3);
                *(uint32_t*)&sDdT[dv * RST + i0]     = pk2(d0 * e0, d1 * e1);
                *(uint32_t*)&sDdT[dv * RST + i0 + 2] = pk2(d2 * e2, d3 * e3);
            }
        }
        __syncthreads();   // D

        // ---- O = eG*(Q ST) + Wqk . Delta (wave pair: rows 16rg, dv half dh) ----
        ffrag accO[4];
#pragma unroll
        for (int nt = 0; nt < 4; ++nt) accO[nt] = (ffrag)0.f;
#pragma unroll
        for (int kk = 0; kk < 4; ++kk) {
            bfrag af = *(const bfrag*)&sQs[(16 * rg + l16) * RSK + 32 * kk + quad8];
#pragma unroll
            for (int nt = 0; nt < 4; ++nt) {
                bfrag bf = *(const bfrag*)&sSTb[(64 * dh + 16 * nt + l16) * RSK + 32 * kk + quad8];
                accO[nt] = __builtin_amdgcn_mfma_f32_16x16x32_bf16(af, bf, accO[nt], 0, 0, 0);
            }
        }
#pragma unroll
        for (int nt = 0; nt < 4; ++nt)
#pragma unroll
            for (int reg = 0; reg < 4; ++reg)
                accO[nt][reg] *= sEG[16 * rg + quad * 4 + reg];
#pragma unroll
        for (int kk = 0; kk < 2; ++kk) {
            bfrag af = *(const bfrag*)&sWqk[(16 * rg + l16) * RST + 32 * kk + quad8];
#pragma unroll
            for (int nt = 0; nt < 4; ++nt) {
                bfrag bf = *(const bfrag*)&sDT[(64 * dh + 16 * nt + l16) * RST + 32 * kk + quad8];
                accO[nt] = __builtin_amdgcn_mfma_f32_16x16x32_bf16(af, bf, accO[nt], 0, 0, 0);
            }
        }

        // RMSNorm partials for this dv-half (combine with partner wave after E)
        float p4[4];
#pragma unroll
        for (int reg = 0; reg < 4; ++reg) {
            float p = 0.f;
#pragma unroll
            for (int nt = 0; nt < 4; ++nt) p += accO[nt][reg] * accO[nt][reg];
#pragma unroll
            for (int m = 1; m < 16; m <<= 1) p += __shfl_xor(p, m, 64);
            p4[reg] = p;
        }
        if (l16 == 0) {
#pragma unroll
            for (int reg = 0; reg < 4; ++reg) sP[w * 16 + quad * 4 + reg] = p4[reg];
        }

        // ---- state update: ST = eGc*ST + DdT . KT (own dv rows; within-wave) ----
        {
            const float eGc = sEG[63];
#pragma unroll
            for (int nt = 0; nt < 8; ++nt)
#pragma unroll
                for (int reg = 0; reg < 4; ++reg) accS[nt][reg] *= eGc;
#pragma unroll
            for (int kk = 0; kk < 2; ++kk) {
                bfrag a0 = *(const bfrag*)&sDdT[(16 * w + l16) * RST + 32 * kk + quad8];
#pragma unroll
                for (int nt = 0; nt < 8; ++nt) {
                    const int ck = 16 * nt + l16;
                    bfrag bk = *(const bfrag*)&sKT[ck * RST +
                                 ((((4 * kk + quad) ^ (ck >> 3)) & 7) << 3)];
                    accS[nt] = __builtin_amdgcn_mfma_f32_16x16x32_bf16(a0, bk, accS[nt], 0, 0, 0);
                }
            }
        }
        __syncthreads();   // E: all STb/DT/DdT/KT reads done; sP written

        // ---- epilogue: combine pair partials, gated RMSNorm, write y over z ----
        {
            float inv[4];
#pragma unroll
            for (int reg = 0; reg < 4; ++reg) {
                float pp = p4[reg] + sP[(w ^ 1) * 16 + quad * 4 + reg];
                inv[reg] = rsqrtf(pp * (1.f / 128.f) + EPS);
            }
            unsigned short* zw =
                z_io + (bL + l0 + 16 * rg + quad * 4) * (size_t)VAL_DIM + h * DV + 64 * dh + l16;
#pragma unroll
            for (int nt = 0; nt < 4; ++nt) {
                const float nwv = sNW[64 * dh + 16 * nt + l16];
#pragma unroll
                for (int reg = 0; reg < 4; ++reg) {
                    float zv = bf2f(pz[nt][reg]);
                    float y = accO[nt][reg] * inv[reg] * nwv * (zv / (1.f + __expf(-zv)));
                    zw[(size_t)reg * VAL_DIM + 16 * nt] = f2bf(y);
                }
            }
        }

        // ---- materialize STb (bf16) for next chunk (own dv rows) ----
#pragma unroll
        for (int nt = 0; nt < 8; ++nt)
#pragma unroll
            for (int reg = 0; reg < 4; ++reg)
                sSTb[(16 * w + quad * 4 + reg) * RSK + 16 * nt + l16] = f2bf(accS[nt][reg]);
    }
}

// ---------------- launch ----------------
extern "C" void kernel_launch(void* const* d_in, const int* in_sizes, int n_in,
                              void* d_out, int out_size, void* d_ws, size_t ws_size,
                              hipStream_t stream)
{
    const float* x        = (const float*)d_in[0];
    const float* W_qkv    = (const float*)d_in[1];
    const float* W_z      = (const float*)d_in[2];
    const float* W_a      = (const float*)d_in[3];
    const float* W_b      = (const float*)d_in[4];
    const float* conv_w   = (const float*)d_in[5];
    const float* A_log    = (const float*)d_in[6];
    const float* dt_bias  = (const float*)d_in[7];
    const float* norm_w   = (const float*)d_in[8];
    const float* W_out    = (const float*)d_in[9];
    float* out = (float*)d_out;
    char*  ws  = (char*)d_ws;

    if (ws_size < WS_NEED_BYTES) return;

    unsigned short* qkv = (unsigned short*)(ws + OFF_QKV);
    unsigned short* z   = (unsigned short*)(ws + OFF_Z);
    float* a    = (float*)(ws + OFF_A);
    float* bbuf = (float*)(ws + OFF_B);
    float* gl   = (float*)(ws + OFF_G);
    float* beta = (float*)(ws + OFF_BETA);
    float* Ubuf = (float*)(ws + OFF_U);
    unsigned short* Wqkbuf = (unsigned short*)(ws + OFF_WQK);
    unsigned short* hbuf   = (unsigned short*)(ws + OFF_HALO);
    unsigned short* Wcat   = (unsigned short*)(ws + OFF_WCAT);  // overlay on U
    unsigned short* xb     = (unsigned short*)(ws + OFF_XB);    // overlay on Wqk
    unsigned short* Wob    = (unsigned short*)(ws + OFF_WOB);   // overlay on U

    static bool attr_set = false;
    if (!attr_set) {
        (void)hipFuncSetAttribute((const void*)chunk_prep,
                                  hipFuncAttributeMaxDynamicSharedMemorySize, P1_SMEM);
        (void)hipFuncSetAttribute((const void*)chunk_scan2,
                                  hipFuncAttributeMaxDynamicSharedMemorySize, P2_SMEM);
        (void)hipFuncSetAttribute((const void*)gemm_inproj_bf,
                                  hipFuncAttributeMaxDynamicSharedMemorySize, GEMM_SMEM);
        (void)hipFuncSetAttribute((const void*)gemm_outproj_bf,
                                  hipFuncAttributeMaxDynamicSharedMemorySize, GEMM_SMEM);
        attr_set = true;
    }

    // 0. pre-convert operands to bf16 (Wcat overlays U-region, xb overlays Wqk-region)
    cvt_wcat<<<NPAD, 256, 0, stream>>>(W_qkv, W_z, W_a, W_b, Wcat);
    cvt_f32bf<<<(int)ROWS, 256, 0, stream>>>(x, xb, DIM);
    // 1. fused input projections (bf16 MFMA GEMM, 3-deep counted-vmcnt pipeline)
    gemm_inproj_bf<<<((int)ROWS / 256) * (NPAD / 128), 512, GEMM_SMEM, stream>>>(
        xb, Wcat, qkv, z, a, bbuf);
    // 2. depthwise causal conv + silu (L-tiled, halo snapshot first)
    conv_halo<<<(B * CONV_LT * CONV_DIM) / 256, 256, 0, stream>>>(qkv, hbuf);
    conv_silu<<<(B * CONV_LT * CONV_DIM) / 256, 256, 0, stream>>>(qkv, conv_w, hbuf);
    // 3. l2norm q,k heads
    normqk<<<(B * L * 2 * HK) / 4, 256, 0, stream>>>(qkv);
    // 4. gate coefficients (log-space g)
    gatecoef<<<(B * L * HV) / 256, 256, 0, stream>>>(a, bbuf, A_log, dt_bias, gl, beta);
    // 5a. parallel chunk prep: A, Wqk, solve -> U (f32, overwrites Wcat), Wkn (v-slot)
    chunk_prep<<<NCH_TOT, 256, P1_SMEM, stream>>>(qkv, gl, beta, Ubuf, Wqkbuf);
    // 5b. sequential scan (8 waves, pipelined): Delta/O/state + fused gated RMSNorm
    chunk_scan2<<<B * HV, 512, P2_SMEM, stream>>>(qkv, gl, Ubuf, Wqkbuf, z, norm_w);
    // 5c. convert W_out to bf16 (U dead now; overlay)
    cvt_f32bf<<<DIM, 256, 0, stream>>>(W_out, Wob, VAL_DIM);
    // 6. output projection (bf16 MFMA GEMM, same pipeline; 256 blocks = 1 round)
    gemm_outproj_bf<<<((int)ROWS / 256) * (DIM / 128), 512, GEMM_SMEM, stream>>>(z, Wob, out);
}